// Round 7
// baseline (1277.734 us; speedup 1.0000x reference)
//
#include <hip/hip_runtime.h>

// PNLM: patch (15x15) non-local attention + projection + residual.
// k_qk   : QK projections; Q|K results bounced through LDS -> fully coalesced
//          640B-row stores to qkws[hw][Q160|K160]. Optionally also writes
//          xbb[blk][c][240] (blocked bf16 x copy) from staging registers.
// k_attn_b: big-ws path: K in LDS, att^T MFMA, lane-local softmax, PV from
//          coalesced xbb rows, proj, bf16 residual from xbb (L2-hot).
// k_attn_s: R6-exact fallback (scattered fp32 x gather + fp32 residual).
// NO v_cvt_pk_bf16_f32 inline asm anywhere (convicted of NaN in R2/R3/R5).

typedef __bf16 bf16x8 __attribute__((ext_vector_type(8)));
typedef float  f32x4  __attribute__((ext_vector_type(4)));

#define MFMA(a,b,c) __builtin_amdgcn_mfma_f32_16x16x32_bf16((a),(b),(c),0,0,0)

#define QK_ROW 320            // Q cols 0..159 (144+ zero), K cols 160..319 (144+ zero)
#define KL_STRIDE 168         // kl row stride in ushorts (336B: 16B-aligned)
#define XBB_ROW 240           // xbb row length (m 0..224 real, 225..239 unwritten-benign)

__device__ __forceinline__ unsigned short f2bf(float f){
  union { float f; unsigned int u; } v; v.f = f;
  unsigned int r = v.u + 0x7FFFu + ((v.u >> 16) & 1u);   // RNE
  return (unsigned short)(r >> 16);
}
__device__ __forceinline__ float bf2f(unsigned short u){
  union { unsigned int u; float f; } v; v.u = ((unsigned int)u) << 16;
  return v.f;
}
// 16B-block XOR swizzle for [rows][256] bf16 LDS tiles (write&read same involution).
__device__ __forceinline__ int swz(int row, int col){
  return row*256 + ((((col >> 3) ^ (row & 7)) << 3) | (col & 7));
}
__device__ __forceinline__ bf16x8 ld_frag_lds(const unsigned short* p, int idx){
  uint4 v = *(const uint4*)(p + idx);
  return __builtin_bit_cast(bf16x8, v);
}
__device__ __forceinline__ bf16x8 ld_frag_b(const void* p){
  uint4 v = *(const uint4*)p;
  return __builtin_bit_cast(bf16x8, v);
}

// D-layout (col=lane&15, rows 4*(lane>>4)+jj per 16-tile) -> operand-frag layout.
__device__ __forceinline__ void repack_frag(const unsigned int* plo, const unsigned int* phi,
                                            uint4* outf, int lane){
  const int nn = lane & 15, hh = lane >> 4;
  const int sla = nn + 32*(hh & 1);
  const int slb = sla + 16;
  const bool up = hh >= 2;
  #pragma unroll
  for (int k = 0; k < 8; ++k){
    unsigned int a0 = (unsigned int)__shfl((int)plo[2*k],   sla);
    unsigned int a1 = (unsigned int)__shfl((int)plo[2*k+1], sla);
    unsigned int b0 = (unsigned int)__shfl((int)phi[2*k],   sla);
    unsigned int b1 = (unsigned int)__shfl((int)phi[2*k+1], sla);
    unsigned int c0 = (unsigned int)__shfl((int)plo[2*k],   slb);
    unsigned int c1 = (unsigned int)__shfl((int)plo[2*k+1], slb);
    unsigned int d0 = (unsigned int)__shfl((int)phi[2*k],   slb);
    unsigned int d1 = (unsigned int)__shfl((int)phi[2*k+1], slb);
    outf[k] = make_uint4(up?a1:a0, up?b1:b0, up?c1:c0, up?d1:d0);
  }
}

// ---------------- kernel 1: QK projections + optional xbb --------------------
__global__ __launch_bounds__(512) void k_qk(
    const float* __restrict__ x, const float* __restrict__ wq,
    const float* __restrict__ wk,
    unsigned short* __restrict__ qkws, unsigned short* __restrict__ xbb)
{
  // S: union( xt[128][256] swizzled (65,536B), ol[128][320] (81,920B) )
  __shared__ __align__(16) unsigned short S[128*320];
  __shared__ unsigned short wqs[32*256];
  __shared__ unsigned short wks[32*256];
  unsigned short* xt = S;
  unsigned short* ol = S;
  const int wg  = blockIdx.x;
  const int b   = wg / 450;
  const int hw0 = (wg % 450) * 128;
  const int tid = threadIdx.x;
  const int lane = tid & 63, wave = tid >> 6;
  const int col  = lane & 15, hi = lane >> 4;

  { // stage X^T (fp32 -> bf16), coalesced reads over hw; optional xbb scatter
    const float* xb = x + (size_t)b * 256 * 57600 + hw0;
    const int hw_l = tid & 127;
    size_t bb = 0;
    if (xbb){
      int hw = hw0 + hw_l;
      int h = hw / 240, w = hw - h*240;
      int th = h / 15, r = h - th*15;
      int tw = w / 15, s = w - tw*15;
      bb = (size_t)(b*256 + th*16 + tw) * (256*XBB_ROW) + (r*15 + s);
    }
    #pragma unroll 4
    for (int i = 0; i < 32; ++i){
      int cp = (tid >> 7) * 32 + i;      // 0..127
      int c  = cp * 2;
      float f0 = xb[(size_t)c     * 57600 + hw_l];
      float f1 = xb[(size_t)(c+1) * 57600 + hw_l];
      unsigned short u0 = f2bf(f0), u1 = f2bf(f1);
      *(unsigned int*)(&xt[swz(hw_l, c)]) =
          (unsigned int)u0 | ((unsigned int)u1 << 16);
      if (xbb){
        xbb[bb + (size_t)c    *XBB_ROW] = u0;
        xbb[bb + (size_t)(c+1)*XBB_ROW] = u1;
      }
    }
  }
  __syncthreads();

  bf16x8 af[8];                          // A-frags: this wave's 16 hw rows
  const int arow = wave*16 + col;
  #pragma unroll
  for (int k = 0; k < 8; ++k)
    af[k] = ld_frag_lds(xt, swz(arow, k*32 + hi*8));
  __syncthreads();                       // all af-loads done -> xt dead, ol live

  for (int eg = 0; eg < 5; ++eg){        // e-groups of 32 (e_pad=160, zeros>=144)
    __syncthreads();
    for (int i = 0; i < 8; ++i){
      int idx = tid + i*512;             // 0..4095
      int e_l = idx >> 7, c = (idx & 127) * 2;
      int e = eg*32 + e_l;
      float2 vq = make_float2(0.f,0.f), vk = make_float2(0.f,0.f);
      if (e < 144){
        vq = *(const float2*)(wq + (size_t)e*256 + c);
        vk = *(const float2*)(wk + (size_t)e*256 + c);
      }
      *(unsigned int*)(&wqs[swz(e_l, c)]) =
          (unsigned int)f2bf(vq.x) | ((unsigned int)f2bf(vq.y) << 16);
      *(unsigned int*)(&wks[swz(e_l, c)]) =
          (unsigned int)f2bf(vk.x) | ((unsigned int)f2bf(vk.y) << 16);
    }
    __syncthreads();
    #pragma unroll
    for (int etl = 0; etl < 2; ++etl){
      f32x4 aq = {0.f,0.f,0.f,0.f}, ak = {0.f,0.f,0.f,0.f};
      const int el = etl*16 + col;
      #pragma unroll
      for (int k = 0; k < 8; ++k){
        int idx = swz(el, k*32 + hi*8);
        bf16x8 bq = ld_frag_lds(wqs, idx);
        bf16x8 bk = ld_frag_lds(wks, idx);
        aq = MFMA(af[k], bq, aq);
        ak = MFMA(af[k], bk, ak);
      }
      const int e_out = eg*32 + etl*16 + col;
      const int rb = wave*16 + hi*4;
      #pragma unroll
      for (int jj = 0; jj < 4; ++jj){
        ol[(rb + jj)*QK_ROW + e_out]       = f2bf(aq[jj]);
        ol[(rb + jj)*QK_ROW + 160 + e_out] = f2bf(ak[jj]);
      }
    }
  }
  __syncthreads();

  { // fully-coalesced bulk store: 128 rows x 640B
    const size_t gbase = ((size_t)b*57600 + hw0) * QK_ROW;
    for (int i = tid; i < 128*40; i += 512){
      int r = i / 40, k2 = i - r*40;
      *(uint4*)(qkws + gbase + (size_t)r*QK_ROW + k2*8) =
          *(const uint4*)(ol + r*QK_ROW + k2*8);
    }
  }
}

// ============ k_attn common phases as a macro-free pair of kernels ===========
// (b-path: xbb-fed PV + bf16 residual; s-path: R6-exact fp32 gather/residual)

__global__ __launch_bounds__(512,4) void k_attn_b(
    const unsigned short* __restrict__ xbb, const float* __restrict__ wproj,
    const unsigned short* __restrict__ qkws, float* __restrict__ out)
{
  __shared__ __align__(16) unsigned short S[40320 + 480];
  unsigned short* kl = S;
  unsigned short* xl = S;
  unsigned short* wl = S + 32768;
  unsigned int*  hwp = (unsigned int*)(S + 40320);
  const int wg = blockIdx.x;
  const int b  = wg >> 8;
  const int th = (wg >> 4) & 15, tw = wg & 15;
  const int h0 = th*15, w0 = tw*15;
  const int tid = threadIdx.x;
  const int lane = tid & 63, wave = tid >> 6;
  const int col  = lane & 15, hi = lane >> 4;
  const size_t obase = (size_t)b * 256 * 57600;
  const unsigned short* qkb = qkws + (size_t)b * 57600 * QK_ROW;
  const unsigned short* xbw = xbb + (size_t)wg * (256*XBB_ROW);

  if (tid < 240){
    int ms = tid <= 224 ? tid : 224;
    hwp[tid] = (unsigned int)((h0 + ms/15)*240 + w0 + ms%15);
  }
  __syncthreads();

  // ---- P0: stage K rows into kl (coalesced) ----
  for (int i = tid; i < 240*20; i += 512){
    int m = i / 20, eb = i - m*20;
    *(uint4*)(&kl[m*KL_STRIDE + eb*8]) =
        *(const uint4*)(qkb + (size_t)hwp[m]*QK_ROW + 160 + eb*8);
  }
  __syncthreads();

  // ---- P1: att^T strips + lane-local softmax + register repack ----
  uint4 attf[2][8];
  #pragma unroll
  for (int slot = 0; slot < 2; ++slot){
    const int nt = wave + slot*8;
    if (nt < 15){
      const int n  = nt*16 + col;
      const int na = n <= 224 ? n : 224;
      const unsigned short* qrow = qkb + (size_t)hwp[na]*QK_ROW;
      bf16x8 qf[5];
      #pragma unroll
      for (int c = 0; c < 5; ++c)
        qf[c] = ld_frag_b(qrow + c*32 + hi*8);
      f32x4 at[15];
      #pragma unroll
      for (int T = 0; T < 15; ++T){
        f32x4 acc = {0.f,0.f,0.f,0.f};
        #pragma unroll
        for (int c = 0; c < 5; ++c){
          bf16x8 kf = ld_frag_lds(kl, (T*16 + col)*KL_STRIDE + c*32 + hi*8);
          acc = MFMA(kf, qf[c], acc);             // att^T[m][n]
        }
        at[T] = acc;
      }
      const float sc = 0.12022458674074695f;      // log2(e)/12
      float M = -3.0e38f;
      #pragma unroll
      for (int T = 0; T < 15; ++T){
        #pragma unroll
        for (int jj = 0; jj < 4; ++jj){
          int m = T*16 + hi*4 + jj;
          if (m <= 224) M = fmaxf(M, at[T][jj]*sc);
        }
      }
      M = fmaxf(M, __shfl_xor(M, 16));
      M = fmaxf(M, __shfl_xor(M, 32));
      float Ssum = 0.f;
      #pragma unroll
      for (int T = 0; T < 15; ++T){
        #pragma unroll
        for (int jj = 0; jj < 4; ++jj){
          int m = T*16 + hi*4 + jj;
          float v = (m <= 224) ? exp2f(at[T][jj]*sc - M) : 0.f;
          at[T][jj] = v; Ssum += v;
        }
      }
      Ssum += __shfl_xor(Ssum, 16);
      Ssum += __shfl_xor(Ssum, 32);
      const float inv = 1.0f / Ssum;
      unsigned int plo[16], phi[16];
      #pragma unroll
      for (int T = 0; T < 15; ++T){
        plo[T] = (unsigned int)f2bf(at[T][0]*inv) | ((unsigned int)f2bf(at[T][1]*inv) << 16);
        phi[T] = (unsigned int)f2bf(at[T][2]*inv) | ((unsigned int)f2bf(at[T][3]*inv) << 16);
      }
      plo[15] = 0u; phi[15] = 0u;
      repack_frag(plo, phi, attf[slot], lane);
    }
  }

  // ---- P2/P3: X from xbb (coalesced rows) into xl; PV partials bf16 ----
  unsigned int ylo[2][16], yhi[2][16];
  #pragma unroll
  for (int half = 0; half < 2; ++half){
    __syncthreads();
    for (int i = tid; i < 128*32; i += 512){
      int c = i >> 5, m8 = i & 31;
      uint4 v = make_uint4(0u,0u,0u,0u);
      if (m8 < 30)
        v = *(const uint4*)(xbw + (size_t)(half*128 + c)*XBB_ROW + m8*8);
      *(uint4*)(&xl[swz(c, m8*8)]) = v;
    }
    __syncthreads();
    #pragma unroll
    for (int slot = 0; slot < 2; ++slot){
      const int nt = wave + slot*8;
      if (nt < 15){
        #pragma unroll
        for (int ct = 0; ct < 8; ++ct){
          f32x4 acc = {0.f,0.f,0.f,0.f};
          #pragma unroll
          for (int k = 0; k < 8; ++k){
            bf16x8 xf = ld_frag_lds(xl, swz(ct*16 + col, k*32 + hi*8));
            acc = MFMA(xf, __builtin_bit_cast(bf16x8, attf[slot][k]), acc);
          }
          ylo[slot][half*8 + ct] = (unsigned int)f2bf(acc[0]) | ((unsigned int)f2bf(acc[1]) << 16);
          yhi[slot][half*8 + ct] = (unsigned int)f2bf(acc[2]) | ((unsigned int)f2bf(acc[3]) << 16);
        }
      }
    }
  }

  uint4 y1f[2][8];
  #pragma unroll
  for (int slot = 0; slot < 2; ++slot){
    const int nt = wave + slot*8;
    if (nt < 15)
      repack_frag(ylo[slot], yhi[slot], y1f[slot], lane);
  }

  // ---- P4: projection + bf16 residual from xbb (L2-hot) ----
  #pragma unroll 1
  for (int oe = 0; oe < 16; ++oe){
    __syncthreads();
    for (int i = tid; i < 16*128; i += 512){
      int olr = i >> 7, c = (i & 127)*2;
      const float* wr = wproj + (size_t)(oe*16 + olr)*256 + c;
      *(unsigned int*)(&wl[swz(olr, c)]) =
          (unsigned int)f2bf(wr[0]) | ((unsigned int)f2bf(wr[1]) << 16);
    }
    __syncthreads();
    bf16x8 awf[8];
    #pragma unroll
    for (int k = 0; k < 8; ++k)
      awf[k] = ld_frag_lds(wl, swz(col, k*32 + hi*8));
    #pragma unroll
    for (int slot = 0; slot < 2; ++slot){
      const int nt = wave + slot*8;
      if (nt < 15){
        f32x4 y2 = {0.f,0.f,0.f,0.f};
        #pragma unroll
        for (int k = 0; k < 8; ++k)
          y2 = MFMA(awf[k], __builtin_bit_cast(bf16x8, y1f[slot][k]), y2);
        const int n = nt*16 + col;
        if (n <= 224){
          const size_t pix = hwp[n];
          #pragma unroll
          for (int jj = 0; jj < 4; ++jj){
            int o = oe*16 + hi*4 + jj;
            float xr = bf2f(xbw[(size_t)o*XBB_ROW + n]);
            out[obase + (size_t)o*57600 + pix] = y2[jj] + xr;
          }
        }
      }
    }
  }
}

// ---------------- R6-exact fallback (small ws) -------------------------------
__global__ __launch_bounds__(512,4) void k_attn_s(
    const float* __restrict__ x, const float* __restrict__ wproj,
    const unsigned short* __restrict__ qkws, float* __restrict__ out)
{
  __shared__ __align__(16) unsigned short S[40320 + 480];
  unsigned short* kl = S;
  unsigned short* xl = S;
  unsigned short* wl = S + 32768;
  unsigned int*  hwp = (unsigned int*)(S + 40320);
  const int wg = blockIdx.x;
  const int b  = wg >> 8;
  const int th = (wg >> 4) & 15, tw = wg & 15;
  const int h0 = th*15, w0 = tw*15;
  const int tid = threadIdx.x;
  const int lane = tid & 63, wave = tid >> 6;
  const int col  = lane & 15, hi = lane >> 4;
  const size_t xbase = (size_t)b * 256 * 57600;
  const unsigned short* qkb = qkws + (size_t)b * 57600 * QK_ROW;

  if (tid < 240){
    int ms = tid <= 224 ? tid : 224;
    hwp[tid] = (unsigned int)((h0 + ms/15)*240 + w0 + ms%15);
  }
  __syncthreads();

  for (int i = tid; i < 240*20; i += 512){
    int m = i / 20, eb = i - m*20;
    *(uint4*)(&kl[m*KL_STRIDE + eb*8]) =
        *(const uint4*)(qkb + (size_t)hwp[m]*QK_ROW + 160 + eb*8);
  }
  __syncthreads();

  uint4 attf[2][8];
  #pragma unroll
  for (int slot = 0; slot < 2; ++slot){
    const int nt = wave + slot*8;
    if (nt < 15){
      const int n  = nt*16 + col;
      const int na = n <= 224 ? n : 224;
      const unsigned short* qrow = qkb + (size_t)hwp[na]*QK_ROW;
      bf16x8 qf[5];
      #pragma unroll
      for (int c = 0; c < 5; ++c)
        qf[c] = ld_frag_b(qrow + c*32 + hi*8);
      f32x4 at[15];
      #pragma unroll
      for (int T = 0; T < 15; ++T){
        f32x4 acc = {0.f,0.f,0.f,0.f};
        #pragma unroll
        for (int c = 0; c < 5; ++c){
          bf16x8 kf = ld_frag_lds(kl, (T*16 + col)*KL_STRIDE + c*32 + hi*8);
          acc = MFMA(kf, qf[c], acc);
        }
        at[T] = acc;
      }
      const float sc = 0.12022458674074695f;
      float M = -3.0e38f;
      #pragma unroll
      for (int T = 0; T < 15; ++T){
        #pragma unroll
        for (int jj = 0; jj < 4; ++jj){
          int m = T*16 + hi*4 + jj;
          if (m <= 224) M = fmaxf(M, at[T][jj]*sc);
        }
      }
      M = fmaxf(M, __shfl_xor(M, 16));
      M = fmaxf(M, __shfl_xor(M, 32));
      float Ssum = 0.f;
      #pragma unroll
      for (int T = 0; T < 15; ++T){
        #pragma unroll
        for (int jj = 0; jj < 4; ++jj){
          int m = T*16 + hi*4 + jj;
          float v = (m <= 224) ? exp2f(at[T][jj]*sc - M) : 0.f;
          at[T][jj] = v; Ssum += v;
        }
      }
      Ssum += __shfl_xor(Ssum, 16);
      Ssum += __shfl_xor(Ssum, 32);
      const float inv = 1.0f / Ssum;
      unsigned int plo[16], phi[16];
      #pragma unroll
      for (int T = 0; T < 15; ++T){
        plo[T] = (unsigned int)f2bf(at[T][0]*inv) | ((unsigned int)f2bf(at[T][1]*inv) << 16);
        phi[T] = (unsigned int)f2bf(at[T][2]*inv) | ((unsigned int)f2bf(at[T][3]*inv) << 16);
      }
      plo[15] = 0u; phi[15] = 0u;
      repack_frag(plo, phi, attf[slot], lane);
    }
  }

  unsigned int ylo[2][16], yhi[2][16];
  #pragma unroll
  for (int half = 0; half < 2; ++half){
    __syncthreads();
    for (int i = tid; i < 128*128; i += 512){
      int c = i >> 7, m = (i & 127)*2;
      int m0 = m <= 224 ? m : 224;
      float f0 = (m     <= 224) ? x[xbase + (size_t)(half*128 + c)*57600 + hwp[m0]]   : 0.f;
      float f1 = (m + 1 <= 224) ? x[xbase + (size_t)(half*128 + c)*57600 + hwp[m0+1]] : 0.f;
      *(unsigned int*)(&xl[swz(c, m)]) =
          (unsigned int)f2bf(f0) | ((unsigned int)f2bf(f1) << 16);
    }
    __syncthreads();
    #pragma unroll
    for (int slot = 0; slot < 2; ++slot){
      const int nt = wave + slot*8;
      if (nt < 15){
        #pragma unroll
        for (int ct = 0; ct < 8; ++ct){
          f32x4 acc = {0.f,0.f,0.f,0.f};
          #pragma unroll
          for (int k = 0; k < 8; ++k){
            bf16x8 xf = ld_frag_lds(xl, swz(ct*16 + col, k*32 + hi*8));
            acc = MFMA(xf, __builtin_bit_cast(bf16x8, attf[slot][k]), acc);
          }
          ylo[slot][half*8 + ct] = (unsigned int)f2bf(acc[0]) | ((unsigned int)f2bf(acc[1]) << 16);
          yhi[slot][half*8 + ct] = (unsigned int)f2bf(acc[2]) | ((unsigned int)f2bf(acc[3]) << 16);
        }
      }
    }
  }

  uint4 y1f[2][8];
  #pragma unroll
  for (int slot = 0; slot < 2; ++slot){
    const int nt = wave + slot*8;
    if (nt < 15)
      repack_frag(ylo[slot], yhi[slot], y1f[slot], lane);
  }

  #pragma unroll 1
  for (int oe = 0; oe < 16; ++oe){
    __syncthreads();
    for (int i = tid; i < 16*128; i += 512){
      int olr = i >> 7, c = (i & 127)*2;
      const float* wr = wproj + (size_t)(oe*16 + olr)*256 + c;
      *(unsigned int*)(&wl[swz(olr, c)]) =
          (unsigned int)f2bf(wr[0]) | ((unsigned int)f2bf(wr[1]) << 16);
    }
    __syncthreads();
    bf16x8 awf[8];
    #pragma unroll
    for (int k = 0; k < 8; ++k)
      awf[k] = ld_frag_lds(wl, swz(col, k*32 + hi*8));
    #pragma unroll
    for (int slot = 0; slot < 2; ++slot){
      const int nt = wave + slot*8;
      if (nt < 15){
        f32x4 y2 = {0.f,0.f,0.f,0.f};
        #pragma unroll
        for (int k = 0; k < 8; ++k)
          y2 = MFMA(awf[k], __builtin_bit_cast(bf16x8, y1f[slot][k]), y2);
        const int n = nt*16 + col;
        if (n <= 224){
          const size_t pix = hwp[n];
          #pragma unroll
          for (int jj = 0; jj < 4; ++jj){
            int o = oe*16 + hi*4 + jj;
            const size_t idx = xbase + (size_t)o*57600 + pix;
            out[idx] = y2[jj] + x[idx];
          }
        }
      }
    }
  }
}

extern "C" void kernel_launch(void* const* d_in, const int* in_sizes, int n_in,
                              void* d_out, int out_size, void* d_ws, size_t ws_size,
                              hipStream_t stream)
{
  const float* x     = (const float*)d_in[0];
  const float* wq    = (const float*)d_in[1];
  const float* wk    = (const float*)d_in[2];
  const float* wproj = (const float*)d_in[3];
  float* out = (float*)d_out;
  (void)in_sizes; (void)n_in; (void)out_size;

  const size_t QKWS_B = (size_t)8*57600*QK_ROW*2;        // 294,912,000
  const size_t XBB_B  = (size_t)8*256*256*XBB_ROW*2;     // 251,658,240
  unsigned short* qkws = (unsigned short*)d_ws;

  if (ws_size >= QKWS_B + XBB_B){
    unsigned short* xbb = (unsigned short*)((char*)d_ws + QKWS_B);
    k_qk    <<<dim3(3600), dim3(512), 0, stream>>>(x, wq, wk, qkws, xbb);
    k_attn_b<<<dim3(2048), dim3(512), 0, stream>>>(xbb, wproj, qkws, out);
  } else {
    k_qk    <<<dim3(3600), dim3(512), 0, stream>>>(x, wq, wk, qkws, nullptr);
    k_attn_s<<<dim3(2048), dim3(512), 0, stream>>>(x, wproj, qkws, out);
  }
}

// Round 8
// 1261.030 us; speedup vs baseline: 1.0132x; 1.0132x over previous
//
#include <hip/hip_runtime.h>

// PNLM: patch (15x15) non-local attention + projection + residual.
// k_xb  : x (raster fp32) -> xbb[blk][c][240] bf16, LDS-staged transpose,
//         coalesced on BOTH sides (960B-run reads, 480B-run writes).
// k_qk  : R6-proven projection; wqs/wks aliased over dead xt -> 2 WG/CU.
// k_attn_b: K in LDS, att^T MFMA, lane-local softmax, reg-staged PV from xbb,
//         8-oe projection with wproj reg-prefetch, bf16 residual, XCD chunking.
// k_attn_s: R6-exact fallback for small ws.
// NO v_cvt_pk_bf16_f32 inline asm anywhere (convicted of NaN in R2/R3/R5).

typedef __bf16 bf16x8 __attribute__((ext_vector_type(8)));
typedef float  f32x4  __attribute__((ext_vector_type(4)));

#define MFMA(a,b,c) __builtin_amdgcn_mfma_f32_16x16x32_bf16((a),(b),(c),0,0,0)

#define QK_ROW 320            // Q cols 0..159 (144+ zero), K cols 160..319 (144+ zero)
#define KL_STRIDE 168         // kl row stride in ushorts (336B: 16B-aligned, spread banks)
#define XBB_ROW 240           // xbb row length in ushorts (480B); m>224 zero

__device__ __forceinline__ unsigned short f2bf(float f){
  union { float f; unsigned int u; } v; v.f = f;
  unsigned int r = v.u + 0x7FFFu + ((v.u >> 16) & 1u);   // RNE
  return (unsigned short)(r >> 16);
}
__device__ __forceinline__ float bf2f(unsigned short u){
  union { unsigned int u; float f; } v; v.u = ((unsigned int)u) << 16;
  return v.f;
}
__device__ __forceinline__ int swz(int row, int col){
  return row*256 + ((((col >> 3) ^ (row & 7)) << 3) | (col & 7));
}
__device__ __forceinline__ bf16x8 ld_frag_lds(const unsigned short* p, int idx){
  uint4 v = *(const uint4*)(p + idx);
  return __builtin_bit_cast(bf16x8, v);
}
__device__ __forceinline__ bf16x8 ld_frag_b(const void* p){
  uint4 v = *(const uint4*)(p);
  return __builtin_bit_cast(bf16x8, v);
}

__device__ __forceinline__ void repack_frag(const unsigned int* plo, const unsigned int* phi,
                                            uint4* outf, int lane){
  const int nn = lane & 15, hh = lane >> 4;
  const int sla = nn + 32*(hh & 1);
  const int slb = sla + 16;
  const bool up = hh >= 2;
  #pragma unroll
  for (int k = 0; k < 8; ++k){
    unsigned int a0 = (unsigned int)__shfl((int)plo[2*k],   sla);
    unsigned int a1 = (unsigned int)__shfl((int)plo[2*k+1], sla);
    unsigned int b0 = (unsigned int)__shfl((int)phi[2*k],   sla);
    unsigned int b1 = (unsigned int)__shfl((int)phi[2*k+1], sla);
    unsigned int c0 = (unsigned int)__shfl((int)plo[2*k],   slb);
    unsigned int c1 = (unsigned int)__shfl((int)plo[2*k+1], slb);
    unsigned int d0 = (unsigned int)__shfl((int)phi[2*k],   slb);
    unsigned int d1 = (unsigned int)__shfl((int)phi[2*k+1], slb);
    outf[k] = make_uint4(up?a1:a0, up?b1:b0, up?c1:c0, up?d1:d0);
  }
}

// ---------------- kernel 0: x -> xbb blocked transpose -----------------------
__global__ __launch_bounds__(256) void k_xb(
    const float* __restrict__ x, unsigned short* __restrict__ xbb)
{
  __shared__ unsigned short xs[8*15*240];   // [c8][r][w] bf16, 57,600 B
  const int wg = blockIdx.x;                // b(8) x th(16) x cg(32)
  const int cg = wg & 31;
  const int th = (wg >> 5) & 15;
  const int b  = wg >> 9;
  const int tid = threadIdx.x;

  const float* xb = x + ((size_t)b*256 + cg*8)*57600 + th*15*240;
  for (int i = tid; i < 8*15*120; i += 256){     // float2 over 240-px rows
    int c = i / 1800;
    int rem = i - c*1800;
    int r = rem / 120, p2 = rem - r*120;
    float2 v = *(const float2*)(xb + (size_t)c*57600 + r*240 + p2*2);
    *(unsigned int*)(&xs[(c*15 + r)*240 + p2*2]) =
        (unsigned int)f2bf(v.x) | ((unsigned int)f2bf(v.y) << 16);
  }
  __syncthreads();

  for (int i = tid; i < 8*16*30; i += 256){      // (c, tw, chunk-of-8)
    int c = i / 480;
    int rem = i - c*480;
    int tw = rem / 30, ch = rem - tw*30;
    union { unsigned short u16[8]; uint4 u4; } pk;
    #pragma unroll
    for (int j = 0; j < 8; ++j){
      int m = ch*8 + j;
      int r = m / 15, s = m - r*15;
      pk.u16[j] = (m <= 224) ? xs[(c*15 + r)*240 + tw*15 + s] : (unsigned short)0;
    }
    *(uint4*)(xbb + ((size_t)(b*256 + th*16 + tw)*256 + cg*8 + c)*XBB_ROW + ch*8) = pk.u4;
  }
}

// ---------------- kernel 1: QK projections (R6 + weight-alias) ---------------
__global__ __launch_bounds__(512) void k_qk(
    const float* __restrict__ x, const float* __restrict__ wq,
    const float* __restrict__ wk,
    unsigned short* __restrict__ qkws)
{
  // xt[128][256] swizzled; wqs/wks alias xt's first 32KB (xt dead after af).
  __shared__ __align__(16) unsigned short S[32768];   // 65,536 B -> 2 WG/CU
  unsigned short* xt  = S;
  unsigned short* wqs = S;
  unsigned short* wks = S + 8192;
  const int wg  = blockIdx.x;
  const int b   = wg / 450;
  const int hw0 = (wg % 450) * 128;
  const int tid = threadIdx.x;
  const int lane = tid & 63, wave = tid >> 6;
  const int col  = lane & 15, hi = lane >> 4;

  { // stage X^T (fp32 -> bf16), coalesced reads over hw
    const float* xb = x + (size_t)b * 256 * 57600 + hw0;
    const int hw_l = tid & 127;
    #pragma unroll 4
    for (int i = 0; i < 32; ++i){
      int c = ((tid >> 7) * 32 + i) * 2;
      float f0 = xb[(size_t)c     * 57600 + hw_l];
      float f1 = xb[(size_t)(c+1) * 57600 + hw_l];
      *(unsigned int*)(&xt[swz(hw_l, c)]) =
          (unsigned int)f2bf(f0) | ((unsigned int)f2bf(f1) << 16);
    }
  }
  __syncthreads();

  bf16x8 af[8];                          // A-frags: this wave's 16 hw rows
  const int arow = wave*16 + col;
  #pragma unroll
  for (int k = 0; k < 8; ++k)
    af[k] = ld_frag_lds(xt, swz(arow, k*32 + hi*8));

  const size_t orow_base = (size_t)b*57600 + hw0 + wave*16;

  for (int eg = 0; eg < 5; ++eg){        // e-groups of 32 (e_pad=160, zeros>=144)
    __syncthreads();                     // af-loads / prev MFMA reads done
    for (int i = 0; i < 8; ++i){
      int idx = tid + i*512;             // 0..4095
      int e_l = idx >> 7, c = (idx & 127) * 2;
      int e = eg*32 + e_l;
      float2 vq = make_float2(0.f,0.f), vk = make_float2(0.f,0.f);
      if (e < 144){
        vq = *(const float2*)(wq + (size_t)e*256 + c);
        vk = *(const float2*)(wk + (size_t)e*256 + c);
      }
      *(unsigned int*)(&wqs[swz(e_l, c)]) =
          (unsigned int)f2bf(vq.x) | ((unsigned int)f2bf(vq.y) << 16);
      *(unsigned int*)(&wks[swz(e_l, c)]) =
          (unsigned int)f2bf(vk.x) | ((unsigned int)f2bf(vk.y) << 16);
    }
    __syncthreads();
    #pragma unroll
    for (int etl = 0; etl < 2; ++etl){
      f32x4 aq = {0.f,0.f,0.f,0.f}, ak = {0.f,0.f,0.f,0.f};
      const int el = etl*16 + col;
      #pragma unroll
      for (int k = 0; k < 8; ++k){
        int idx = swz(el, k*32 + hi*8);
        bf16x8 bq = ld_frag_lds(wqs, idx);
        bf16x8 bk = ld_frag_lds(wks, idx);
        aq = MFMA(af[k], bq, aq);
        ak = MFMA(af[k], bk, ak);
      }
      const int e_out = eg*32 + etl*16 + col;
      #pragma unroll
      for (int jj = 0; jj < 4; ++jj){
        size_t row = orow_base + hi*4 + jj;
        qkws[row*QK_ROW + e_out]       = f2bf(aq[jj]);
        qkws[row*QK_ROW + 160 + e_out] = f2bf(ak[jj]);
      }
    }
  }
}

// ---------------- kernel 2 (big ws): attention + PV + proj + residual --------
__global__ __launch_bounds__(512,4) void k_attn_b(
    const unsigned short* __restrict__ xbb, const float* __restrict__ wproj,
    const unsigned short* __restrict__ qkws, float* __restrict__ out)
{
  // Region S (81,920 B exactly -> 2 WG/CU):
  //   P0/P1: kl[240][168]        (80,640 B)
  //   P2+  : xl[128][256] swz    (65,536 B) | wl[32][256] swz (16,384 B)
  __shared__ __align__(16) unsigned short S[40960];
  unsigned short* kl = S;
  unsigned short* xl = S;
  unsigned short* wl = S + 32768;
  // XCD chunking: each XCD gets a contiguous range of work-ids (m157 chunked)
  const int wg = ((int)blockIdx.x & 7)*256 + ((int)blockIdx.x >> 3);
  const int b  = wg >> 8;
  const int th = (wg >> 4) & 15, tw = wg & 15;
  const int h0 = th*15, w0 = tw*15;
  const int tid = threadIdx.x;
  const int lane = tid & 63, wave = tid >> 6;
  const int col  = lane & 15, hi = lane >> 4;
  const size_t obase = (size_t)b * 256 * 57600;
  const unsigned short* qkb = qkws + (size_t)b * 57600 * QK_ROW;
  const unsigned short* xbw = xbb + (size_t)wg * (256*XBB_ROW);

  // ---- P0: stage K rows into kl (coalesced); early-issue Q loads ----
  for (int i = tid; i < 240*20; i += 512){
    int m = i / 20, eb = i - m*20;
    int ms = m <= 224 ? m : 224;
    int hw = (h0 + ms/15)*240 + w0 + ms%15;
    *(uint4*)(&kl[m*KL_STRIDE + eb*8]) =
        *(const uint4*)(qkb + (size_t)hw*QK_ROW + 160 + eb*8);
  }
  uint4 qraw[2][5];
  #pragma unroll
  for (int slot = 0; slot < 2; ++slot){
    const int nt = wave + slot*8;
    if (nt < 15){
      const int n  = nt*16 + col;
      const int na = n <= 224 ? n : 224;
      const unsigned short* qrow = qkb + (size_t)((h0 + na/15)*240 + w0 + na%15)*QK_ROW;
      #pragma unroll
      for (int c = 0; c < 5; ++c)
        qraw[slot][c] = *(const uint4*)(qrow + c*32 + hi*8);
    }
  }
  __syncthreads();

  // ---- P1: att^T strips + lane-local softmax + register repack ----
  uint4 attf[2][8];
  #pragma unroll
  for (int slot = 0; slot < 2; ++slot){
    const int nt = wave + slot*8;
    if (nt < 15){
      f32x4 at[15];
      #pragma unroll
      for (int T = 0; T < 15; ++T){
        f32x4 acc = {0.f,0.f,0.f,0.f};
        #pragma unroll
        for (int c = 0; c < 5; ++c){
          bf16x8 kf = ld_frag_lds(kl, (T*16 + col)*KL_STRIDE + c*32 + hi*8);
          acc = MFMA(kf, __builtin_bit_cast(bf16x8, qraw[slot][c]), acc);
        }
        at[T] = acc;
      }
      const float sc = 0.12022458674074695f;      // log2(e)/12
      float M = -3.0e38f;
      #pragma unroll
      for (int T = 0; T < 15; ++T){
        #pragma unroll
        for (int jj = 0; jj < 4; ++jj){
          int m = T*16 + hi*4 + jj;
          if (m <= 224) M = fmaxf(M, at[T][jj]*sc);
        }
      }
      M = fmaxf(M, __shfl_xor(M, 16));
      M = fmaxf(M, __shfl_xor(M, 32));
      float Ssum = 0.f;
      #pragma unroll
      for (int T = 0; T < 15; ++T){
        #pragma unroll
        for (int jj = 0; jj < 4; ++jj){
          int m = T*16 + hi*4 + jj;
          float v = (m <= 224) ? exp2f(at[T][jj]*sc - M) : 0.f;
          at[T][jj] = v; Ssum += v;
        }
      }
      Ssum += __shfl_xor(Ssum, 16);
      Ssum += __shfl_xor(Ssum, 32);
      const float inv = 1.0f / Ssum;
      unsigned int plo[16], phi[16];
      #pragma unroll
      for (int T = 0; T < 15; ++T){
        plo[T] = (unsigned int)f2bf(at[T][0]*inv) | ((unsigned int)f2bf(at[T][1]*inv) << 16);
        phi[T] = (unsigned int)f2bf(at[T][2]*inv) | ((unsigned int)f2bf(at[T][3]*inv) << 16);
      }
      plo[15] = 0u; phi[15] = 0u;
      repack_frag(plo, phi, attf[slot], lane);
    }
  }

  // ---- P2/P3: reg-staged X halves from xbb (issue-early / write-late) ----
  unsigned int ylo[2][16], yhi[2][16];
  uint4 xst[8];
  #pragma unroll
  for (int j = 0; j < 8; ++j){                    // half0 loads (overlap P1 tail)
    int i = tid + j*512;
    int c = i >> 5, m8 = i & 31;
    xst[j] = make_uint4(0u,0u,0u,0u);
    if (m8 < 30) xst[j] = *(const uint4*)(xbw + (size_t)c*XBB_ROW + m8*8);
  }
  __syncthreads();                                // kl readers done -> xl writable
  #pragma unroll
  for (int j = 0; j < 8; ++j){
    int i = tid + j*512;
    int c = i >> 5, m8 = i & 31;
    *(uint4*)(&xl[swz(c, m8*8)]) = xst[j];
  }
  uint4 xst1[8];
  #pragma unroll
  for (int j = 0; j < 8; ++j){                    // half1 loads (overlap PV0)
    int i = tid + j*512;
    int c = i >> 5, m8 = i & 31;
    xst1[j] = make_uint4(0u,0u,0u,0u);
    if (m8 < 30) xst1[j] = *(const uint4*)(xbw + (size_t)(128 + c)*XBB_ROW + m8*8);
  }
  __syncthreads();                                // xl(half0) ready
  #pragma unroll
  for (int slot = 0; slot < 2; ++slot){
    const int nt = wave + slot*8;
    if (nt < 15){
      #pragma unroll
      for (int ct = 0; ct < 8; ++ct){
        f32x4 acc = {0.f,0.f,0.f,0.f};
        #pragma unroll
        for (int k = 0; k < 8; ++k){
          bf16x8 xf = ld_frag_lds(xl, swz(ct*16 + col, k*32 + hi*8));
          acc = MFMA(xf, __builtin_bit_cast(bf16x8, attf[slot][k]), acc);
        }
        ylo[slot][ct] = (unsigned int)f2bf(acc[0]) | ((unsigned int)f2bf(acc[1]) << 16);
        yhi[slot][ct] = (unsigned int)f2bf(acc[2]) | ((unsigned int)f2bf(acc[3]) << 16);
      }
    }
  }
  __syncthreads();                                // PV0 readers done
  #pragma unroll
  for (int j = 0; j < 8; ++j){
    int i = tid + j*512;
    int c = i >> 5, m8 = i & 31;
    *(uint4*)(&xl[swz(c, m8*8)]) = xst1[j];
  }
  __syncthreads();                                // xl(half1) ready
  #pragma unroll
  for (int slot = 0; slot < 2; ++slot){
    const int nt = wave + slot*8;
    if (nt < 15){
      #pragma unroll
      for (int ct = 0; ct < 8; ++ct){
        f32x4 acc = {0.f,0.f,0.f,0.f};
        #pragma unroll
        for (int k = 0; k < 8; ++k){
          bf16x8 xf = ld_frag_lds(xl, swz(ct*16 + col, k*32 + hi*8));
          acc = MFMA(xf, __builtin_bit_cast(bf16x8, attf[slot][k]), acc);
        }
        ylo[slot][8 + ct] = (unsigned int)f2bf(acc[0]) | ((unsigned int)f2bf(acc[1]) << 16);
        yhi[slot][8 + ct] = (unsigned int)f2bf(acc[2]) | ((unsigned int)f2bf(acc[3]) << 16);
      }
    }
  }

  uint4 y1f[2][8];
  #pragma unroll
  for (int slot = 0; slot < 2; ++slot){
    const int nt = wave + slot*8;
    if (nt < 15)
      repack_frag(ylo[slot], yhi[slot], y1f[slot], lane);
  }

  // ---- P4: projection, 8 oe chunks of 32 rows, wproj reg-prefetch ----
  float2 wpf[8];
  #pragma unroll
  for (int j = 0; j < 8; ++j){
    int i = tid + j*512;
    int olr = i >> 7, c = (i & 127)*2;
    wpf[j] = *(const float2*)(wproj + (size_t)olr*256 + c);
  }
  #pragma unroll 1
  for (int oe = 0; oe < 8; ++oe){
    __syncthreads();                              // prev wl readers done
    #pragma unroll
    for (int j = 0; j < 8; ++j){
      int i = tid + j*512;
      int olr = i >> 7, c = (i & 127)*2;
      *(unsigned int*)(&wl[swz(olr, c)]) =
          (unsigned int)f2bf(wpf[j].x) | ((unsigned int)f2bf(wpf[j].y) << 16);
    }
    if (oe < 7){
      #pragma unroll
      for (int j = 0; j < 8; ++j){
        int i = tid + j*512;
        int olr = i >> 7, c = (i & 127)*2;
        wpf[j] = *(const float2*)(wproj + (size_t)((oe+1)*32 + olr)*256 + c);
      }
    }
    __syncthreads();
    #pragma unroll
    for (int ot = 0; ot < 2; ++ot){
      bf16x8 awf[8];
      const int olr = ot*16 + col;
      #pragma unroll
      for (int k = 0; k < 8; ++k)
        awf[k] = ld_frag_lds(wl, swz(olr, k*32 + hi*8));
      #pragma unroll
      for (int slot = 0; slot < 2; ++slot){
        const int nt = wave + slot*8;
        if (nt < 15){
          f32x4 y2 = {0.f,0.f,0.f,0.f};
          #pragma unroll
          for (int k = 0; k < 8; ++k)
            y2 = MFMA(awf[k], __builtin_bit_cast(bf16x8, y1f[slot][k]), y2);
          const int n = nt*16 + col;
          if (n <= 224){
            const size_t pix = (size_t)(h0 + n/15)*240 + w0 + n%15;
            #pragma unroll
            for (int jj = 0; jj < 4; ++jj){
              int o = oe*32 + ot*16 + hi*4 + jj;
              float xr = bf2f(xbw[(size_t)o*XBB_ROW + n]);
              out[obase + (size_t)o*57600 + pix] = y2[jj] + xr;
            }
          }
        }
      }
    }
  }
}

// ---------------- R6-exact fallback (small ws) -------------------------------
__global__ __launch_bounds__(512,4) void k_attn_s(
    const float* __restrict__ x, const float* __restrict__ wproj,
    const unsigned short* __restrict__ qkws, float* __restrict__ out)
{
  __shared__ __align__(16) unsigned short S[40320 + 480];
  unsigned short* kl = S;
  unsigned short* xl = S;
  unsigned short* wl = S + 32768;
  unsigned int*  hwp = (unsigned int*)(S + 40320);
  const int wg = blockIdx.x;
  const int b  = wg >> 8;
  const int th = (wg >> 4) & 15, tw = wg & 15;
  const int h0 = th*15, w0 = tw*15;
  const int tid = threadIdx.x;
  const int lane = tid & 63, wave = tid >> 6;
  const int col  = lane & 15, hi = lane >> 4;
  const size_t xbase = (size_t)b * 256 * 57600;
  const unsigned short* qkb = qkws + (size_t)b * 57600 * QK_ROW;

  if (tid < 240){
    int ms = tid <= 224 ? tid : 224;
    hwp[tid] = (unsigned int)((h0 + ms/15)*240 + w0 + ms%15);
  }
  __syncthreads();

  for (int i = tid; i < 240*20; i += 512){
    int m = i / 20, eb = i - m*20;
    *(uint4*)(&kl[m*KL_STRIDE + eb*8]) =
        *(const uint4*)(qkb + (size_t)hwp[m]*QK_ROW + 160 + eb*8);
  }
  __syncthreads();

  uint4 attf[2][8];
  #pragma unroll
  for (int slot = 0; slot < 2; ++slot){
    const int nt = wave + slot*8;
    if (nt < 15){
      const int n  = nt*16 + col;
      const int na = n <= 224 ? n : 224;
      const unsigned short* qrow = qkb + (size_t)hwp[na]*QK_ROW;
      bf16x8 qf[5];
      #pragma unroll
      for (int c = 0; c < 5; ++c)
        qf[c] = ld_frag_b(qrow + c*32 + hi*8);
      f32x4 at[15];
      #pragma unroll
      for (int T = 0; T < 15; ++T){
        f32x4 acc = {0.f,0.f,0.f,0.f};
        #pragma unroll
        for (int c = 0; c < 5; ++c){
          bf16x8 kf = ld_frag_lds(kl, (T*16 + col)*KL_STRIDE + c*32 + hi*8);
          acc = MFMA(kf, qf[c], acc);
        }
        at[T] = acc;
      }
      const float sc = 0.12022458674074695f;
      float M = -3.0e38f;
      #pragma unroll
      for (int T = 0; T < 15; ++T){
        #pragma unroll
        for (int jj = 0; jj < 4; ++jj){
          int m = T*16 + hi*4 + jj;
          if (m <= 224) M = fmaxf(M, at[T][jj]*sc);
        }
      }
      M = fmaxf(M, __shfl_xor(M, 16));
      M = fmaxf(M, __shfl_xor(M, 32));
      float Ssum = 0.f;
      #pragma unroll
      for (int T = 0; T < 15; ++T){
        #pragma unroll
        for (int jj = 0; jj < 4; ++jj){
          int m = T*16 + hi*4 + jj;
          float v = (m <= 224) ? exp2f(at[T][jj]*sc - M) : 0.f;
          at[T][jj] = v; Ssum += v;
        }
      }
      Ssum += __shfl_xor(Ssum, 16);
      Ssum += __shfl_xor(Ssum, 32);
      const float inv = 1.0f / Ssum;
      unsigned int plo[16], phi[16];
      #pragma unroll
      for (int T = 0; T < 15; ++T){
        plo[T] = (unsigned int)f2bf(at[T][0]*inv) | ((unsigned int)f2bf(at[T][1]*inv) << 16);
        phi[T] = (unsigned int)f2bf(at[T][2]*inv) | ((unsigned int)f2bf(at[T][3]*inv) << 16);
      }
      plo[15] = 0u; phi[15] = 0u;
      repack_frag(plo, phi, attf[slot], lane);
    }
  }

  unsigned int ylo[2][16], yhi[2][16];
  #pragma unroll
  for (int half = 0; half < 2; ++half){
    __syncthreads();
    for (int i = tid; i < 128*128; i += 512){
      int c = i >> 7, m = (i & 127)*2;
      int m0 = m <= 224 ? m : 224;
      float f0 = (m     <= 224) ? x[xbase + (size_t)(half*128 + c)*57600 + hwp[m0]]   : 0.f;
      float f1 = (m + 1 <= 224) ? x[xbase + (size_t)(half*128 + c)*57600 + hwp[m0+1]] : 0.f;
      *(unsigned int*)(&xl[swz(c, m)]) =
          (unsigned int)f2bf(f0) | ((unsigned int)f2bf(f1) << 16);
    }
    __syncthreads();
    #pragma unroll
    for (int slot = 0; slot < 2; ++slot){
      const int nt = wave + slot*8;
      if (nt < 15){
        #pragma unroll
        for (int ct = 0; ct < 8; ++ct){
          f32x4 acc = {0.f,0.f,0.f,0.f};
          #pragma unroll
          for (int k = 0; k < 8; ++k){
            bf16x8 xf = ld_frag_lds(xl, swz(ct*16 + col, k*32 + hi*8));
            acc = MFMA(xf, __builtin_bit_cast(bf16x8, attf[slot][k]), acc);
          }
          ylo[slot][half*8 + ct] = (unsigned int)f2bf(acc[0]) | ((unsigned int)f2bf(acc[1]) << 16);
          yhi[slot][half*8 + ct] = (unsigned int)f2bf(acc[2]) | ((unsigned int)f2bf(acc[3]) << 16);
        }
      }
    }
  }

  uint4 y1f[2][8];
  #pragma unroll
  for (int slot = 0; slot < 2; ++slot){
    const int nt = wave + slot*8;
    if (nt < 15)
      repack_frag(ylo[slot], yhi[slot], y1f[slot], lane);
  }

  #pragma unroll 1
  for (int oe = 0; oe < 16; ++oe){
    __syncthreads();
    for (int i = tid; i < 16*128; i += 512){
      int olr = i >> 7, c = (i & 127)*2;
      const float* wr = wproj + (size_t)(oe*16 + olr)*256 + c;
      *(unsigned int*)(&wl[swz(olr, c)]) =
          (unsigned int)f2bf(wr[0]) | ((unsigned int)f2bf(wr[1]) << 16);
    }
    __syncthreads();
    bf16x8 awf[8];
    #pragma unroll
    for (int k = 0; k < 8; ++k)
      awf[k] = ld_frag_lds(wl, swz(col, k*32 + hi*8));
    #pragma unroll
    for (int slot = 0; slot < 2; ++slot){
      const int nt = wave + slot*8;
      if (nt < 15){
        f32x4 y2 = {0.f,0.f,0.f,0.f};
        #pragma unroll
        for (int k = 0; k < 8; ++k)
          y2 = MFMA(awf[k], __builtin_bit_cast(bf16x8, y1f[slot][k]), y2);
        const int n = nt*16 + col;
        if (n <= 224){
          const size_t pix = hwp[n];
          #pragma unroll
          for (int jj = 0; jj < 4; ++jj){
            int o = oe*16 + hi*4 + jj;
            const size_t idx = xbase + (size_t)o*57600 + pix;
            out[idx] = y2[jj] + x[idx];
          }
        }
      }
    }
  }
}

extern "C" void kernel_launch(void* const* d_in, const int* in_sizes, int n_in,
                              void* d_out, int out_size, void* d_ws, size_t ws_size,
                              hipStream_t stream)
{
  const float* x     = (const float*)d_in[0];
  const float* wq    = (const float*)d_in[1];
  const float* wk    = (const float*)d_in[2];
  const float* wproj = (const float*)d_in[3];
  float* out = (float*)d_out;
  (void)in_sizes; (void)n_in; (void)out_size;

  const size_t QKWS_B = (size_t)8*57600*QK_ROW*2;        // 294,912,000
  const size_t XBB_B  = (size_t)8*256*256*XBB_ROW*2;     // 251,658,240
  unsigned short* qkws = (unsigned short*)d_ws;

  if (ws_size >= QKWS_B + XBB_B){
    unsigned short* xbb = (unsigned short*)((char*)d_ws + QKWS_B);
    k_xb    <<<dim3(4096), dim3(256), 0, stream>>>(x, xbb);
    k_qk    <<<dim3(3600), dim3(512), 0, stream>>>(x, wq, wk, qkws);
    k_attn_b<<<dim3(2048), dim3(512), 0, stream>>>(xbb, wproj, qkws, out);
  } else {
    k_qk    <<<dim3(3600), dim3(512), 0, stream>>>(x, wq, wk, qkws);
    k_attn_s<<<dim3(2048), dim3(512), 0, stream>>>(x, wproj, qkws, out);
  }
}

// Round 9
// 1083.092 us; speedup vs baseline: 1.1797x; 1.1643x over previous
//
#include <hip/hip_runtime.h>

// PNLM: patch (15x15) non-local attention + projection + residual.
// k_xb  : x (raster fp32) -> xbb[blk][c][240] bf16, LDS-staged transpose (R8-proven).
// k_qk  : projection, wqs/wks aliased over dead xt -> 2 WG/CU (R8-proven).
// k_attn_b: R7-verbatim: K in LDS, att^T MFMA, lane-local softmax, LDS-staged
//         PV from xbb, wl-sixteenth projection, bf16 residual. Low reg pressure.
// k_attn_s: R6-exact fallback for small ws.
// NO v_cvt_pk_bf16_f32 inline asm (convicted of NaN R2/R3/R5).

typedef __bf16 bf16x8 __attribute__((ext_vector_type(8)));
typedef float  f32x4  __attribute__((ext_vector_type(4)));

#define MFMA(a,b,c) __builtin_amdgcn_mfma_f32_16x16x32_bf16((a),(b),(c),0,0,0)

#define QK_ROW 320            // Q cols 0..159 (144+ zero), K cols 160..319 (144+ zero)
#define KL_STRIDE 168         // kl row stride in ushorts (336B: 16B-aligned)
#define XBB_ROW 240           // xbb row length in ushorts (480B); m>224 zero

__device__ __forceinline__ unsigned short f2bf(float f){
  union { float f; unsigned int u; } v; v.f = f;
  unsigned int r = v.u + 0x7FFFu + ((v.u >> 16) & 1u);   // RNE
  return (unsigned short)(r >> 16);
}
__device__ __forceinline__ float bf2f(unsigned short u){
  union { unsigned int u; float f; } v; v.u = ((unsigned int)u) << 16;
  return v.f;
}
__device__ __forceinline__ int swz(int row, int col){
  return row*256 + ((((col >> 3) ^ (row & 7)) << 3) | (col & 7));
}
__device__ __forceinline__ bf16x8 ld_frag_lds(const unsigned short* p, int idx){
  uint4 v = *(const uint4*)(p + idx);
  return __builtin_bit_cast(bf16x8, v);
}
__device__ __forceinline__ bf16x8 ld_frag_b(const void* p){
  uint4 v = *(const uint4*)(p);
  return __builtin_bit_cast(bf16x8, v);
}

__device__ __forceinline__ void repack_frag(const unsigned int* plo, const unsigned int* phi,
                                            uint4* outf, int lane){
  const int nn = lane & 15, hh = lane >> 4;
  const int sla = nn + 32*(hh & 1);
  const int slb = sla + 16;
  const bool up = hh >= 2;
  #pragma unroll
  for (int k = 0; k < 8; ++k){
    unsigned int a0 = (unsigned int)__shfl((int)plo[2*k],   sla);
    unsigned int a1 = (unsigned int)__shfl((int)plo[2*k+1], sla);
    unsigned int b0 = (unsigned int)__shfl((int)phi[2*k],   sla);
    unsigned int b1 = (unsigned int)__shfl((int)phi[2*k+1], sla);
    unsigned int c0 = (unsigned int)__shfl((int)plo[2*k],   slb);
    unsigned int c1 = (unsigned int)__shfl((int)plo[2*k+1], slb);
    unsigned int d0 = (unsigned int)__shfl((int)phi[2*k],   slb);
    unsigned int d1 = (unsigned int)__shfl((int)phi[2*k+1], slb);
    outf[k] = make_uint4(up?a1:a0, up?b1:b0, up?c1:c0, up?d1:d0);
  }
}

// ---------------- kernel 0: x -> xbb blocked transpose (R8-proven) -----------
__global__ __launch_bounds__(256) void k_xb(
    const float* __restrict__ x, unsigned short* __restrict__ xbb)
{
  __shared__ unsigned short xs[8*15*240];   // [c8][r][w] bf16, 57,600 B
  const int wg = blockIdx.x;                // b(8) x th(16) x cg(32)
  const int cg = wg & 31;
  const int th = (wg >> 5) & 15;
  const int b  = wg >> 9;
  const int tid = threadIdx.x;

  const float* xb = x + ((size_t)b*256 + cg*8)*57600 + th*15*240;
  for (int i = tid; i < 8*15*120; i += 256){     // float2 over 240-px rows
    int c = i / 1800;
    int rem = i - c*1800;
    int r = rem / 120, p2 = rem - r*120;
    float2 v = *(const float2*)(xb + (size_t)c*57600 + r*240 + p2*2);
    *(unsigned int*)(&xs[(c*15 + r)*240 + p2*2]) =
        (unsigned int)f2bf(v.x) | ((unsigned int)f2bf(v.y) << 16);
  }
  __syncthreads();

  for (int i = tid; i < 8*16*30; i += 256){      // (c, tw, chunk-of-8)
    int c = i / 480;
    int rem = i - c*480;
    int tw = rem / 30, ch = rem - tw*30;
    union { unsigned short u16[8]; uint4 u4; } pk;
    #pragma unroll
    for (int j = 0; j < 8; ++j){
      int m = ch*8 + j;
      int r = m / 15, s = m - r*15;
      pk.u16[j] = (m <= 224) ? xs[(c*15 + r)*240 + tw*15 + s] : (unsigned short)0;
    }
    *(uint4*)(xbb + ((size_t)(b*256 + th*16 + tw)*256 + cg*8 + c)*XBB_ROW + ch*8) = pk.u4;
  }
}

// ---------------- kernel 1: QK projections (R8-proven) -----------------------
__global__ __launch_bounds__(512) void k_qk(
    const float* __restrict__ x, const float* __restrict__ wq,
    const float* __restrict__ wk,
    unsigned short* __restrict__ qkws)
{
  // xt[128][256] swizzled; wqs/wks alias xt's first 32KB (xt dead after af).
  __shared__ __align__(16) unsigned short S[32768];   // 65,536 B -> 2 WG/CU
  unsigned short* xt  = S;
  unsigned short* wqs = S;
  unsigned short* wks = S + 8192;
  const int wg  = blockIdx.x;
  const int b   = wg / 450;
  const int hw0 = (wg % 450) * 128;
  const int tid = threadIdx.x;
  const int lane = tid & 63, wave = tid >> 6;
  const int col  = lane & 15, hi = lane >> 4;

  { // stage X^T (fp32 -> bf16), coalesced reads over hw
    const float* xb = x + (size_t)b * 256 * 57600 + hw0;
    const int hw_l = tid & 127;
    #pragma unroll 4
    for (int i = 0; i < 32; ++i){
      int c = ((tid >> 7) * 32 + i) * 2;
      float f0 = xb[(size_t)c     * 57600 + hw_l];
      float f1 = xb[(size_t)(c+1) * 57600 + hw_l];
      *(unsigned int*)(&xt[swz(hw_l, c)]) =
          (unsigned int)f2bf(f0) | ((unsigned int)f2bf(f1) << 16);
    }
  }
  __syncthreads();

  bf16x8 af[8];                          // A-frags: this wave's 16 hw rows
  const int arow = wave*16 + col;
  #pragma unroll
  for (int k = 0; k < 8; ++k)
    af[k] = ld_frag_lds(xt, swz(arow, k*32 + hi*8));

  const size_t orow_base = (size_t)b*57600 + hw0 + wave*16;

  for (int eg = 0; eg < 5; ++eg){        // e-groups of 32 (e_pad=160, zeros>=144)
    __syncthreads();                     // af-loads / prev MFMA reads done
    for (int i = 0; i < 8; ++i){
      int idx = tid + i*512;             // 0..4095
      int e_l = idx >> 7, c = (idx & 127) * 2;
      int e = eg*32 + e_l;
      float2 vq = make_float2(0.f,0.f), vk = make_float2(0.f,0.f);
      if (e < 144){
        vq = *(const float2*)(wq + (size_t)e*256 + c);
        vk = *(const float2*)(wk + (size_t)e*256 + c);
      }
      *(unsigned int*)(&wqs[swz(e_l, c)]) =
          (unsigned int)f2bf(vq.x) | ((unsigned int)f2bf(vq.y) << 16);
      *(unsigned int*)(&wks[swz(e_l, c)]) =
          (unsigned int)f2bf(vk.x) | ((unsigned int)f2bf(vk.y) << 16);
    }
    __syncthreads();
    #pragma unroll
    for (int etl = 0; etl < 2; ++etl){
      f32x4 aq = {0.f,0.f,0.f,0.f}, ak = {0.f,0.f,0.f,0.f};
      const int el = etl*16 + col;
      #pragma unroll
      for (int k = 0; k < 8; ++k){
        int idx = swz(el, k*32 + hi*8);
        bf16x8 bq = ld_frag_lds(wqs, idx);
        bf16x8 bk = ld_frag_lds(wks, idx);
        aq = MFMA(af[k], bq, aq);
        ak = MFMA(af[k], bk, ak);
      }
      const int e_out = eg*32 + etl*16 + col;
      #pragma unroll
      for (int jj = 0; jj < 4; ++jj){
        size_t row = orow_base + hi*4 + jj;
        qkws[row*QK_ROW + e_out]       = f2bf(aq[jj]);
        qkws[row*QK_ROW + 160 + e_out] = f2bf(ak[jj]);
      }
    }
  }
}

// ---------------- kernel 2 (big ws): R7-verbatim attention -------------------
__global__ __launch_bounds__(512,4) void k_attn_b(
    const unsigned short* __restrict__ xbb, const float* __restrict__ wproj,
    const unsigned short* __restrict__ qkws, float* __restrict__ out)
{
  __shared__ __align__(16) unsigned short S[40320 + 480];
  unsigned short* kl = S;
  unsigned short* xl = S;
  unsigned short* wl = S + 32768;
  unsigned int*  hwp = (unsigned int*)(S + 40320);
  const int wg = blockIdx.x;
  const int b  = wg >> 8;
  const int th = (wg >> 4) & 15, tw = wg & 15;
  const int h0 = th*15, w0 = tw*15;
  const int tid = threadIdx.x;
  const int lane = tid & 63, wave = tid >> 6;
  const int col  = lane & 15, hi = lane >> 4;
  const size_t obase = (size_t)b * 256 * 57600;
  const unsigned short* qkb = qkws + (size_t)b * 57600 * QK_ROW;
  const unsigned short* xbw = xbb + (size_t)wg * (256*XBB_ROW);

  if (tid < 240){
    int ms = tid <= 224 ? tid : 224;
    hwp[tid] = (unsigned int)((h0 + ms/15)*240 + w0 + ms%15);
  }
  __syncthreads();

  // ---- P0: stage K rows into kl (coalesced) ----
  for (int i = tid; i < 240*20; i += 512){
    int m = i / 20, eb = i - m*20;
    *(uint4*)(&kl[m*KL_STRIDE + eb*8]) =
        *(const uint4*)(qkb + (size_t)hwp[m]*QK_ROW + 160 + eb*8);
  }
  __syncthreads();

  // ---- P1: att^T strips + lane-local softmax + register repack ----
  uint4 attf[2][8];
  #pragma unroll
  for (int slot = 0; slot < 2; ++slot){
    const int nt = wave + slot*8;
    if (nt < 15){
      const int n  = nt*16 + col;
      const int na = n <= 224 ? n : 224;
      const unsigned short* qrow = qkb + (size_t)hwp[na]*QK_ROW;
      bf16x8 qf[5];
      #pragma unroll
      for (int c = 0; c < 5; ++c)
        qf[c] = ld_frag_b(qrow + c*32 + hi*8);
      f32x4 at[15];
      #pragma unroll
      for (int T = 0; T < 15; ++T){
        f32x4 acc = {0.f,0.f,0.f,0.f};
        #pragma unroll
        for (int c = 0; c < 5; ++c){
          bf16x8 kf = ld_frag_lds(kl, (T*16 + col)*KL_STRIDE + c*32 + hi*8);
          acc = MFMA(kf, qf[c], acc);             // att^T[m][n]
        }
        at[T] = acc;
      }
      const float sc = 0.12022458674074695f;      // log2(e)/12
      float M = -3.0e38f;
      #pragma unroll
      for (int T = 0; T < 15; ++T){
        #pragma unroll
        for (int jj = 0; jj < 4; ++jj){
          int m = T*16 + hi*4 + jj;
          if (m <= 224) M = fmaxf(M, at[T][jj]*sc);
        }
      }
      M = fmaxf(M, __shfl_xor(M, 16));
      M = fmaxf(M, __shfl_xor(M, 32));
      float Ssum = 0.f;
      #pragma unroll
      for (int T = 0; T < 15; ++T){
        #pragma unroll
        for (int jj = 0; jj < 4; ++jj){
          int m = T*16 + hi*4 + jj;
          float v = (m <= 224) ? exp2f(at[T][jj]*sc - M) : 0.f;
          at[T][jj] = v; Ssum += v;
        }
      }
      Ssum += __shfl_xor(Ssum, 16);
      Ssum += __shfl_xor(Ssum, 32);
      const float inv = 1.0f / Ssum;
      unsigned int plo[16], phi[16];
      #pragma unroll
      for (int T = 0; T < 15; ++T){
        plo[T] = (unsigned int)f2bf(at[T][0]*inv) | ((unsigned int)f2bf(at[T][1]*inv) << 16);
        phi[T] = (unsigned int)f2bf(at[T][2]*inv) | ((unsigned int)f2bf(at[T][3]*inv) << 16);
      }
      plo[15] = 0u; phi[15] = 0u;
      repack_frag(plo, phi, attf[slot], lane);
    }
  }

  // ---- P2/P3: X from xbb (coalesced rows) into xl; PV partials bf16 ----
  unsigned int ylo[2][16], yhi[2][16];
  #pragma unroll
  for (int half = 0; half < 2; ++half){
    __syncthreads();
    for (int i = tid; i < 128*32; i += 512){
      int c = i >> 5, m8 = i & 31;
      uint4 v = make_uint4(0u,0u,0u,0u);
      if (m8 < 30)
        v = *(const uint4*)(xbw + (size_t)(half*128 + c)*XBB_ROW + m8*8);
      *(uint4*)(&xl[swz(c, m8*8)]) = v;
    }
    __syncthreads();
    #pragma unroll
    for (int slot = 0; slot < 2; ++slot){
      const int nt = wave + slot*8;
      if (nt < 15){
        #pragma unroll
        for (int ct = 0; ct < 8; ++ct){
          f32x4 acc = {0.f,0.f,0.f,0.f};
          #pragma unroll
          for (int k = 0; k < 8; ++k){
            bf16x8 xf = ld_frag_lds(xl, swz(ct*16 + col, k*32 + hi*8));
            acc = MFMA(xf, __builtin_bit_cast(bf16x8, attf[slot][k]), acc);
          }
          ylo[slot][half*8 + ct] = (unsigned int)f2bf(acc[0]) | ((unsigned int)f2bf(acc[1]) << 16);
          yhi[slot][half*8 + ct] = (unsigned int)f2bf(acc[2]) | ((unsigned int)f2bf(acc[3]) << 16);
        }
      }
    }
  }

  uint4 y1f[2][8];
  #pragma unroll
  for (int slot = 0; slot < 2; ++slot){
    const int nt = wave + slot*8;
    if (nt < 15)
      repack_frag(ylo[slot], yhi[slot], y1f[slot], lane);
  }

  // ---- P4: projection + bf16 residual from xbb (L2-hot) ----
  #pragma unroll 1
  for (int oe = 0; oe < 16; ++oe){
    __syncthreads();
    for (int i = tid; i < 16*128; i += 512){
      int olr = i >> 7, c = (i & 127)*2;
      const float* wr = wproj + (size_t)(oe*16 + olr)*256 + c;
      *(unsigned int*)(&wl[swz(olr, c)]) =
          (unsigned int)f2bf(wr[0]) | ((unsigned int)f2bf(wr[1]) << 16);
    }
    __syncthreads();
    bf16x8 awf[8];
    #pragma unroll
    for (int k = 0; k < 8; ++k)
      awf[k] = ld_frag_lds(wl, swz(col, k*32 + hi*8));
    #pragma unroll
    for (int slot = 0; slot < 2; ++slot){
      const int nt = wave + slot*8;
      if (nt < 15){
        f32x4 y2 = {0.f,0.f,0.f,0.f};
        #pragma unroll
        for (int k = 0; k < 8; ++k)
          y2 = MFMA(awf[k], __builtin_bit_cast(bf16x8, y1f[slot][k]), y2);
        const int n = nt*16 + col;
        if (n <= 224){
          const size_t pix = hwp[n];
          #pragma unroll
          for (int jj = 0; jj < 4; ++jj){
            int o = oe*16 + hi*4 + jj;
            float xr = bf2f(xbw[(size_t)o*XBB_ROW + n]);
            out[obase + (size_t)o*57600 + pix] = y2[jj] + xr;
          }
        }
      }
    }
  }
}

// ---------------- R6-exact fallback (small ws) -------------------------------
__global__ __launch_bounds__(512,4) void k_attn_s(
    const float* __restrict__ x, const float* __restrict__ wproj,
    const unsigned short* __restrict__ qkws, float* __restrict__ out)
{
  __shared__ __align__(16) unsigned short S[40320 + 480];
  unsigned short* kl = S;
  unsigned short* xl = S;
  unsigned short* wl = S + 32768;
  unsigned int*  hwp = (unsigned int*)(S + 40320);
  const int wg = blockIdx.x;
  const int b  = wg >> 8;
  const int th = (wg >> 4) & 15, tw = wg & 15;
  const int h0 = th*15, w0 = tw*15;
  const int tid = threadIdx.x;
  const int lane = tid & 63, wave = tid >> 6;
  const int col  = lane & 15, hi = lane >> 4;
  const size_t xbase = (size_t)b * 256 * 57600;
  const unsigned short* qkb = qkws + (size_t)b * 57600 * QK_ROW;

  if (tid < 240){
    int ms = tid <= 224 ? tid : 224;
    hwp[tid] = (unsigned int)((h0 + ms/15)*240 + w0 + ms%15);
  }
  __syncthreads();

  for (int i = tid; i < 240*20; i += 512){
    int m = i / 20, eb = i - m*20;
    *(uint4*)(&kl[m*KL_STRIDE + eb*8]) =
        *(const uint4*)(qkb + (size_t)hwp[m]*QK_ROW + 160 + eb*8);
  }
  __syncthreads();

  uint4 attf[2][8];
  #pragma unroll
  for (int slot = 0; slot < 2; ++slot){
    const int nt = wave + slot*8;
    if (nt < 15){
      const int n  = nt*16 + col;
      const int na = n <= 224 ? n : 224;
      const unsigned short* qrow = qkb + (size_t)hwp[na]*QK_ROW;
      bf16x8 qf[5];
      #pragma unroll
      for (int c = 0; c < 5; ++c)
        qf[c] = ld_frag_b(qrow + c*32 + hi*8);
      f32x4 at[15];
      #pragma unroll
      for (int T = 0; T < 15; ++T){
        f32x4 acc = {0.f,0.f,0.f,0.f};
        #pragma unroll
        for (int c = 0; c < 5; ++c){
          bf16x8 kf = ld_frag_lds(kl, (T*16 + col)*KL_STRIDE + c*32 + hi*8);
          acc = MFMA(kf, qf[c], acc);
        }
        at[T] = acc;
      }
      const float sc = 0.12022458674074695f;
      float M = -3.0e38f;
      #pragma unroll
      for (int T = 0; T < 15; ++T){
        #pragma unroll
        for (int jj = 0; jj < 4; ++jj){
          int m = T*16 + hi*4 + jj;
          if (m <= 224) M = fmaxf(M, at[T][jj]*sc);
        }
      }
      M = fmaxf(M, __shfl_xor(M, 16));
      M = fmaxf(M, __shfl_xor(M, 32));
      float Ssum = 0.f;
      #pragma unroll
      for (int T = 0; T < 15; ++T){
        #pragma unroll
        for (int jj = 0; jj < 4; ++jj){
          int m = T*16 + hi*4 + jj;
          float v = (m <= 224) ? exp2f(at[T][jj]*sc - M) : 0.f;
          at[T][jj] = v; Ssum += v;
        }
      }
      Ssum += __shfl_xor(Ssum, 16);
      Ssum += __shfl_xor(Ssum, 32);
      const float inv = 1.0f / Ssum;
      unsigned int plo[16], phi[16];
      #pragma unroll
      for (int T = 0; T < 15; ++T){
        plo[T] = (unsigned int)f2bf(at[T][0]*inv) | ((unsigned int)f2bf(at[T][1]*inv) << 16);
        phi[T] = (unsigned int)f2bf(at[T][2]*inv) | ((unsigned int)f2bf(at[T][3]*inv) << 16);
      }
      plo[15] = 0u; phi[15] = 0u;
      repack_frag(plo, phi, attf[slot], lane);
    }
  }

  unsigned int ylo[2][16], yhi[2][16];
  #pragma unroll
  for (int half = 0; half < 2; ++half){
    __syncthreads();
    for (int i = tid; i < 128*128; i += 512){
      int c = i >> 7, m = (i & 127)*2;
      int m0 = m <= 224 ? m : 224;
      float f0 = (m     <= 224) ? x[xbase + (size_t)(half*128 + c)*57600 + hwp[m0]]   : 0.f;
      float f1 = (m + 1 <= 224) ? x[xbase + (size_t)(half*128 + c)*57600 + hwp[m0+1]] : 0.f;
      *(unsigned int*)(&xl[swz(c, m)]) =
          (unsigned int)f2bf(f0) | ((unsigned int)f2bf(f1) << 16);
    }
    __syncthreads();
    #pragma unroll
    for (int slot = 0; slot < 2; ++slot){
      const int nt = wave + slot*8;
      if (nt < 15){
        #pragma unroll
        for (int ct = 0; ct < 8; ++ct){
          f32x4 acc = {0.f,0.f,0.f,0.f};
          #pragma unroll
          for (int k = 0; k < 8; ++k){
            bf16x8 xf = ld_frag_lds(xl, swz(ct*16 + col, k*32 + hi*8));
            acc = MFMA(xf, __builtin_bit_cast(bf16x8, attf[slot][k]), acc);
          }
          ylo[slot][half*8 + ct] = (unsigned int)f2bf(acc[0]) | ((unsigned int)f2bf(acc[1]) << 16);
          yhi[slot][half*8 + ct] = (unsigned int)f2bf(acc[2]) | ((unsigned int)f2bf(acc[3]) << 16);
        }
      }
    }
  }

  uint4 y1f[2][8];
  #pragma unroll
  for (int slot = 0; slot < 2; ++slot){
    const int nt = wave + slot*8;
    if (nt < 15)
      repack_frag(ylo[slot], yhi[slot], y1f[slot], lane);
  }

  #pragma unroll 1
  for (int oe = 0; oe < 16; ++oe){
    __syncthreads();
    for (int i = tid; i < 16*128; i += 512){
      int olr = i >> 7, c = (i & 127)*2;
      const float* wr = wproj + (size_t)(oe*16 + olr)*256 + c;
      *(unsigned int*)(&wl[swz(olr, c)]) =
          (unsigned int)f2bf(wr[0]) | ((unsigned int)f2bf(wr[1]) << 16);
    }
    __syncthreads();
    bf16x8 awf[8];
    #pragma unroll
    for (int k = 0; k < 8; ++k)
      awf[k] = ld_frag_lds(wl, swz(col, k*32 + hi*8));
    #pragma unroll
    for (int slot = 0; slot < 2; ++slot){
      const int nt = wave + slot*8;
      if (nt < 15){
        f32x4 y2 = {0.f,0.f,0.f,0.f};
        #pragma unroll
        for (int k = 0; k < 8; ++k)
          y2 = MFMA(awf[k], __builtin_bit_cast(bf16x8, y1f[slot][k]), y2);
        const int n = nt*16 + col;
        if (n <= 224){
          const size_t pix = hwp[n];
          #pragma unroll
          for (int jj = 0; jj < 4; ++jj){
            int o = oe*16 + hi*4 + jj;
            const size_t idx = xbase + (size_t)o*57600 + pix;
            out[idx] = y2[jj] + x[idx];
          }
        }
      }
    }
  }
}

extern "C" void kernel_launch(void* const* d_in, const int* in_sizes, int n_in,
                              void* d_out, int out_size, void* d_ws, size_t ws_size,
                              hipStream_t stream)
{
  const float* x     = (const float*)d_in[0];
  const float* wq    = (const float*)d_in[1];
  const float* wk    = (const float*)d_in[2];
  const float* wproj = (const float*)d_in[3];
  float* out = (float*)d_out;
  (void)in_sizes; (void)n_in; (void)out_size;

  const size_t QKWS_B = (size_t)8*57600*QK_ROW*2;        // 294,912,000
  const size_t XBB_B  = (size_t)8*256*256*XBB_ROW*2;     // 251,658,240
  unsigned short* qkws = (unsigned short*)d_ws;

  if (ws_size >= QKWS_B + XBB_B){
    unsigned short* xbb = (unsigned short*)((char*)d_ws + QKWS_B);
    k_xb    <<<dim3(4096), dim3(256), 0, stream>>>(x, xbb);
    k_qk    <<<dim3(3600), dim3(512), 0, stream>>>(x, wq, wk, qkws);
    k_attn_b<<<dim3(2048), dim3(512), 0, stream>>>(xbb, wproj, qkws, out);
  } else {
    k_qk    <<<dim3(3600), dim3(512), 0, stream>>>(x, wq, wk, qkws);
    k_attn_s<<<dim3(2048), dim3(512), 0, stream>>>(x, wproj, qkws, out);
  }
}

// Round 10
// 1039.574 us; speedup vs baseline: 1.2291x; 1.0419x over previous
//
#include <hip/hip_runtime.h>

// PNLM: patch (15x15) non-local attention + projection + residual.
// k_w   : bf16 weight copies (wqb/wkb zero-padded to [160][256], wpb[256][256]).
// k_xb  : x (raster fp32) -> xbb[blk][c][240] bf16 (R8/R9-proven).
// k_qkb : per-block QK projections FROM xbb (bf16, 4x fewer read bytes than x):
//         m-half X^T transpose into xt (swzC), weights from wqb/wkb aliased
//         over dead xt. Identical arithmetic to k_qk -> absmax unchanged.
// k_qk  : R9-proven raster-tile projection (mid-ws fallback).
// k_attn_b / k_attn_s: R9-frozen.
// NO v_cvt_pk_bf16_f32 inline asm (convicted of NaN R2/R3/R5).

typedef __bf16 bf16x8 __attribute__((ext_vector_type(8)));
typedef float  f32x4  __attribute__((ext_vector_type(4)));

#define MFMA(a,b,c) __builtin_amdgcn_mfma_f32_16x16x32_bf16((a),(b),(c),0,0,0)

#define QK_ROW 320            // Q cols 0..159 (144+ zero), K cols 160..319 (144+ zero)
#define KL_STRIDE 168         // kl row stride in ushorts (336B: 16B-aligned)
#define XBB_ROW 240           // xbb row length in ushorts (480B); m>224 zero

__device__ __forceinline__ unsigned short f2bf(float f){
  union { float f; unsigned int u; } v; v.f = f;
  unsigned int r = v.u + 0x7FFFu + ((v.u >> 16) & 1u);   // RNE
  return (unsigned short)(r >> 16);
}
__device__ __forceinline__ float bf2f(unsigned short u){
  union { unsigned int u; float f; } v; v.u = ((unsigned int)u) << 16;
  return v.f;
}
// 16B-block XOR swizzle for [rows][256] tiles (row&7 varies across read lanes).
__device__ __forceinline__ int swz(int row, int col){
  return row*256 + ((((col >> 3) ^ (row & 7)) << 3) | (col & 7));
}
// Transpose-friendly swizzle: XOR index (row>>3)^row varies for BOTH
// 8-consecutive-row scatter writes (j fixed, m8 varies) and 16-consecutive-row
// fragment reads (lane varies) -> <=4-way banks each side.
__device__ __forceinline__ int swzC(int row, int col){
  return row*256 + (col ^ ((((row >> 3) ^ row) & 7) << 3));
}
__device__ __forceinline__ bf16x8 ld_frag_lds(const unsigned short* p, int idx){
  uint4 v = *(const uint4*)(p + idx);
  return __builtin_bit_cast(bf16x8, v);
}
__device__ __forceinline__ bf16x8 ld_frag_b(const void* p){
  uint4 v = *(const uint4*)(p);
  return __builtin_bit_cast(bf16x8, v);
}

__device__ __forceinline__ void repack_frag(const unsigned int* plo, const unsigned int* phi,
                                            uint4* outf, int lane){
  const int nn = lane & 15, hh = lane >> 4;
  const int sla = nn + 32*(hh & 1);
  const int slb = sla + 16;
  const bool up = hh >= 2;
  #pragma unroll
  for (int k = 0; k < 8; ++k){
    unsigned int a0 = (unsigned int)__shfl((int)plo[2*k],   sla);
    unsigned int a1 = (unsigned int)__shfl((int)plo[2*k+1], sla);
    unsigned int b0 = (unsigned int)__shfl((int)phi[2*k],   sla);
    unsigned int b1 = (unsigned int)__shfl((int)phi[2*k+1], sla);
    unsigned int c0 = (unsigned int)__shfl((int)plo[2*k],   slb);
    unsigned int c1 = (unsigned int)__shfl((int)plo[2*k+1], slb);
    unsigned int d0 = (unsigned int)__shfl((int)phi[2*k],   slb);
    unsigned int d1 = (unsigned int)__shfl((int)phi[2*k+1], slb);
    outf[k] = make_uint4(up?a1:a0, up?b1:b0, up?c1:c0, up?d1:d0);
  }
}

// ---------------- kernel W: bf16 weight copies (zero-padded) -----------------
__global__ __launch_bounds__(256) void k_w(
    const float* __restrict__ wq, const float* __restrict__ wk,
    const float* __restrict__ wproj,
    unsigned short* __restrict__ wqb, unsigned short* __restrict__ wkb,
    unsigned short* __restrict__ wpb)
{
  int i = blockIdx.x*256 + threadIdx.x;             // pair index, grid 288
  if (i < 20480){                                    // wqb [160][256], rows>=144 zero
    int e = i >> 7, c = (i & 127)*2;
    unsigned int v = 0;
    if (e < 144) v = (unsigned int)f2bf(wq[e*256+c]) | ((unsigned int)f2bf(wq[e*256+c+1]) << 16);
    *(unsigned int*)(wqb + (size_t)i*2) = v;
  } else if (i < 40960){                             // wkb [160][256], rows>=144 zero
    int j = i - 20480;
    int e = j >> 7, c = (j & 127)*2;
    unsigned int v = 0;
    if (e < 144) v = (unsigned int)f2bf(wk[e*256+c]) | ((unsigned int)f2bf(wk[e*256+c+1]) << 16);
    *(unsigned int*)(wkb + (size_t)j*2) = v;
  } else if (i < 73728){                             // wpb [256][256]
    int l = i - 40960;
    int o = l >> 7, c = (l & 127)*2;
    *(unsigned int*)(wpb + (size_t)l*2) =
        (unsigned int)f2bf(wproj[o*256+c]) | ((unsigned int)f2bf(wproj[o*256+c+1]) << 16);
  }
}

// ---------------- kernel 0: x -> xbb blocked transpose (R8-proven) -----------
__global__ __launch_bounds__(256) void k_xb(
    const float* __restrict__ x, unsigned short* __restrict__ xbb)
{
  __shared__ unsigned short xs[8*15*240];   // [c8][r][w] bf16, 57,600 B
  const int wg = blockIdx.x;                // b(8) x th(16) x cg(32)
  const int cg = wg & 31;
  const int th = (wg >> 5) & 15;
  const int b  = wg >> 9;
  const int tid = threadIdx.x;

  const float* xb = x + ((size_t)b*256 + cg*8)*57600 + th*15*240;
  for (int i = tid; i < 8*15*120; i += 256){     // float2 over 240-px rows
    int c = i / 1800;
    int rem = i - c*1800;
    int r = rem / 120, p2 = rem - r*120;
    float2 v = *(const float2*)(xb + (size_t)c*57600 + r*240 + p2*2);
    *(unsigned int*)(&xs[(c*15 + r)*240 + p2*2]) =
        (unsigned int)f2bf(v.x) | ((unsigned int)f2bf(v.y) << 16);
  }
  __syncthreads();

  for (int i = tid; i < 8*16*30; i += 256){      // (c, tw, chunk-of-8)
    int c = i / 480;
    int rem = i - c*480;
    int tw = rem / 30, ch = rem - tw*30;
    union { unsigned short u16[8]; uint4 u4; } pk;
    #pragma unroll
    for (int j = 0; j < 8; ++j){
      int m = ch*8 + j;
      int r = m / 15, s = m - r*15;
      pk.u16[j] = (m <= 224) ? xs[(c*15 + r)*240 + tw*15 + s] : (unsigned short)0;
    }
    *(uint4*)(xbb + ((size_t)(b*256 + th*16 + tw)*256 + cg*8 + c)*XBB_ROW + ch*8) = pk.u4;
  }
}

// ---------------- kernel 1b: per-block QK projections from xbb ---------------
__global__ __launch_bounds__(512) void k_qkb(
    const unsigned short* __restrict__ xbb,
    const unsigned short* __restrict__ wqb, const unsigned short* __restrict__ wkb,
    unsigned short* __restrict__ qkws)
{
  // xt[128][256] swzC (65,536B); wqs/wks [32][256] each alias xt rows 0..63
  // (xt consumed into af registers before weights staged). 2 WG/CU.
  __shared__ __align__(16) unsigned short S[32768];
  unsigned short* xt  = S;
  unsigned short* wqs = S;            // 16,384 B (xt rows 0..31 region)
  unsigned short* wks = S + 8192;     // 16,384 B (xt rows 32..63 region)
  const int wg = blockIdx.x;
  const int b  = wg >> 8;
  const int th = (wg >> 4) & 15, tw = wg & 15;
  const int h0 = th*15, w0 = tw*15;
  const int tid = threadIdx.x;
  const int lane = tid & 63, wave = tid >> 6;
  const int col  = lane & 15, hi = lane >> 4;
  const unsigned short* xbw = xbb + (size_t)wg * (256*XBB_ROW);

  #pragma unroll 1
  for (int half = 0; half < 2; ++half){
    if (half) __syncthreads();               // prev eg's w-readers done
    // ---- stage xt: transpose xbb rows [c][m] -> xt [m_local][c] ----
    for (int i = tid; i < 256*16; i += 512){
      int c = i >> 4, m8 = i & 15;
      int m = half*128 + m8*8;
      if (m < 240){
        uint4 v = *(const uint4*)(xbw + (size_t)c*XBB_ROW + m);
        const unsigned short* pv = (const unsigned short*)&v;
        #pragma unroll
        for (int j = 0; j < 8; ++j)
          xt[swzC(m8*8 + j, c)] = pv[j];
      }
    }
    __syncthreads();

    const int t = half*8 + wave;             // this wave's m-tile (0..14)
    const bool act = t < 15;
    bf16x8 af[8];
    if (act){
      const int rloc = wave*16 + col;
      #pragma unroll
      for (int k = 0; k < 8; ++k)
        af[k] = ld_frag_lds(xt, swzC(rloc, k*32 + hi*8));
    }
    __syncthreads();                         // xt consumed -> region free for w

    #pragma unroll 1
    for (int eg = 0; eg < 5; ++eg){
      if (eg) __syncthreads();               // prev MFMA w-reads done
      for (int i = tid; i < 32*32; i += 512){
        int e_l = i >> 5, c8 = (i & 31)*8;
        size_t off = (size_t)(eg*32 + e_l)*256 + c8;
        *(uint4*)(&wqs[swz(e_l, c8)]) = *(const uint4*)(wqb + off);
        *(uint4*)(&wks[swz(e_l, c8)]) = *(const uint4*)(wkb + off);
      }
      __syncthreads();
      if (act){
        #pragma unroll
        for (int et = 0; et < 2; ++et){
          f32x4 aq = {0.f,0.f,0.f,0.f}, ak = {0.f,0.f,0.f,0.f};
          const int el = et*16 + col;
          #pragma unroll
          for (int k = 0; k < 8; ++k){
            int idx = swz(el, k*32 + hi*8);
            bf16x8 bq = ld_frag_lds(wqs, idx);
            bf16x8 bk = ld_frag_lds(wks, idx);
            aq = MFMA(af[k], bq, aq);
            ak = MFMA(af[k], bk, ak);
          }
          const int e_out = eg*32 + et*16 + col;
          #pragma unroll
          for (int jj = 0; jj < 4; ++jj){
            int m_px = t*16 + hi*4 + jj;
            if (m_px <= 224){
              int hw = (h0 + m_px/15)*240 + w0 + m_px%15;
              size_t row = ((size_t)b*57600 + hw)*QK_ROW;
              qkws[row + e_out]       = f2bf(aq[jj]);
              qkws[row + 160 + e_out] = f2bf(ak[jj]);
            }
          }
        }
      }
    }
  }
}

// ---------------- kernel 1: QK projections (R9-proven, mid-ws path) ----------
__global__ __launch_bounds__(512) void k_qk(
    const float* __restrict__ x, const float* __restrict__ wq,
    const float* __restrict__ wk,
    unsigned short* __restrict__ qkws)
{
  __shared__ __align__(16) unsigned short S[32768];
  unsigned short* xt  = S;
  unsigned short* wqs = S;
  unsigned short* wks = S + 8192;
  const int wg  = blockIdx.x;
  const int b   = wg / 450;
  const int hw0 = (wg % 450) * 128;
  const int tid = threadIdx.x;
  const int lane = tid & 63, wave = tid >> 6;
  const int col  = lane & 15, hi = lane >> 4;

  {
    const float* xb = x + (size_t)b * 256 * 57600 + hw0;
    const int hw_l = tid & 127;
    #pragma unroll 4
    for (int i = 0; i < 32; ++i){
      int c = ((tid >> 7) * 32 + i) * 2;
      float f0 = xb[(size_t)c     * 57600 + hw_l];
      float f1 = xb[(size_t)(c+1) * 57600 + hw_l];
      *(unsigned int*)(&xt[swz(hw_l, c)]) =
          (unsigned int)f2bf(f0) | ((unsigned int)f2bf(f1) << 16);
    }
  }
  __syncthreads();

  bf16x8 af[8];
  const int arow = wave*16 + col;
  #pragma unroll
  for (int k = 0; k < 8; ++k)
    af[k] = ld_frag_lds(xt, swz(arow, k*32 + hi*8));

  const size_t orow_base = (size_t)b*57600 + hw0 + wave*16;

  for (int eg = 0; eg < 5; ++eg){
    __syncthreads();
    for (int i = 0; i < 8; ++i){
      int idx = tid + i*512;
      int e_l = idx >> 7, c = (idx & 127) * 2;
      int e = eg*32 + e_l;
      float2 vq = make_float2(0.f,0.f), vk = make_float2(0.f,0.f);
      if (e < 144){
        vq = *(const float2*)(wq + (size_t)e*256 + c);
        vk = *(const float2*)(wk + (size_t)e*256 + c);
      }
      *(unsigned int*)(&wqs[swz(e_l, c)]) =
          (unsigned int)f2bf(vq.x) | ((unsigned int)f2bf(vq.y) << 16);
      *(unsigned int*)(&wks[swz(e_l, c)]) =
          (unsigned int)f2bf(vk.x) | ((unsigned int)f2bf(vk.y) << 16);
    }
    __syncthreads();
    #pragma unroll
    for (int etl = 0; etl < 2; ++etl){
      f32x4 aq = {0.f,0.f,0.f,0.f}, ak = {0.f,0.f,0.f,0.f};
      const int el = etl*16 + col;
      #pragma unroll
      for (int k = 0; k < 8; ++k){
        int idx = swz(el, k*32 + hi*8);
        bf16x8 bq = ld_frag_lds(wqs, idx);
        bf16x8 bk = ld_frag_lds(wks, idx);
        aq = MFMA(af[k], bq, aq);
        ak = MFMA(af[k], bk, ak);
      }
      const int e_out = eg*32 + etl*16 + col;
      #pragma unroll
      for (int jj = 0; jj < 4; ++jj){
        size_t row = orow_base + hi*4 + jj;
        qkws[row*QK_ROW + e_out]       = f2bf(aq[jj]);
        qkws[row*QK_ROW + 160 + e_out] = f2bf(ak[jj]);
      }
    }
  }
}

// ---------------- kernel 2 (big ws): R9-frozen attention ---------------------
__global__ __launch_bounds__(512,4) void k_attn_b(
    const unsigned short* __restrict__ xbb, const float* __restrict__ wproj,
    const unsigned short* __restrict__ qkws, float* __restrict__ out)
{
  __shared__ __align__(16) unsigned short S[40320 + 480];
  unsigned short* kl = S;
  unsigned short* xl = S;
  unsigned short* wl = S + 32768;
  unsigned int*  hwp = (unsigned int*)(S + 40320);
  const int wg = blockIdx.x;
  const int b  = wg >> 8;
  const int th = (wg >> 4) & 15, tw = wg & 15;
  const int h0 = th*15, w0 = tw*15;
  const int tid = threadIdx.x;
  const int lane = tid & 63, wave = tid >> 6;
  const int col  = lane & 15, hi = lane >> 4;
  const size_t obase = (size_t)b * 256 * 57600;
  const unsigned short* qkb = qkws + (size_t)b * 57600 * QK_ROW;
  const unsigned short* xbw = xbb + (size_t)wg * (256*XBB_ROW);

  if (tid < 240){
    int ms = tid <= 224 ? tid : 224;
    hwp[tid] = (unsigned int)((h0 + ms/15)*240 + w0 + ms%15);
  }
  __syncthreads();

  for (int i = tid; i < 240*20; i += 512){
    int m = i / 20, eb = i - m*20;
    *(uint4*)(&kl[m*KL_STRIDE + eb*8]) =
        *(const uint4*)(qkb + (size_t)hwp[m]*QK_ROW + 160 + eb*8);
  }
  __syncthreads();

  uint4 attf[2][8];
  #pragma unroll
  for (int slot = 0; slot < 2; ++slot){
    const int nt = wave + slot*8;
    if (nt < 15){
      const int n  = nt*16 + col;
      const int na = n <= 224 ? n : 224;
      const unsigned short* qrow = qkb + (size_t)hwp[na]*QK_ROW;
      bf16x8 qf[5];
      #pragma unroll
      for (int c = 0; c < 5; ++c)
        qf[c] = ld_frag_b(qrow + c*32 + hi*8);
      f32x4 at[15];
      #pragma unroll
      for (int T = 0; T < 15; ++T){
        f32x4 acc = {0.f,0.f,0.f,0.f};
        #pragma unroll
        for (int c = 0; c < 5; ++c){
          bf16x8 kf = ld_frag_lds(kl, (T*16 + col)*KL_STRIDE + c*32 + hi*8);
          acc = MFMA(kf, qf[c], acc);
        }
        at[T] = acc;
      }
      const float sc = 0.12022458674074695f;
      float M = -3.0e38f;
      #pragma unroll
      for (int T = 0; T < 15; ++T){
        #pragma unroll
        for (int jj = 0; jj < 4; ++jj){
          int m = T*16 + hi*4 + jj;
          if (m <= 224) M = fmaxf(M, at[T][jj]*sc);
        }
      }
      M = fmaxf(M, __shfl_xor(M, 16));
      M = fmaxf(M, __shfl_xor(M, 32));
      float Ssum = 0.f;
      #pragma unroll
      for (int T = 0; T < 15; ++T){
        #pragma unroll
        for (int jj = 0; jj < 4; ++jj){
          int m = T*16 + hi*4 + jj;
          float v = (m <= 224) ? exp2f(at[T][jj]*sc - M) : 0.f;
          at[T][jj] = v; Ssum += v;
        }
      }
      Ssum += __shfl_xor(Ssum, 16);
      Ssum += __shfl_xor(Ssum, 32);
      const float inv = 1.0f / Ssum;
      unsigned int plo[16], phi[16];
      #pragma unroll
      for (int T = 0; T < 15; ++T){
        plo[T] = (unsigned int)f2bf(at[T][0]*inv) | ((unsigned int)f2bf(at[T][1]*inv) << 16);
        phi[T] = (unsigned int)f2bf(at[T][2]*inv) | ((unsigned int)f2bf(at[T][3]*inv) << 16);
      }
      plo[15] = 0u; phi[15] = 0u;
      repack_frag(plo, phi, attf[slot], lane);
    }
  }

  unsigned int ylo[2][16], yhi[2][16];
  #pragma unroll
  for (int half = 0; half < 2; ++half){
    __syncthreads();
    for (int i = tid; i < 128*32; i += 512){
      int c = i >> 5, m8 = i & 31;
      uint4 v = make_uint4(0u,0u,0u,0u);
      if (m8 < 30)
        v = *(const uint4*)(xbw + (size_t)(half*128 + c)*XBB_ROW + m8*8);
      *(uint4*)(&xl[swz(c, m8*8)]) = v;
    }
    __syncthreads();
    #pragma unroll
    for (int slot = 0; slot < 2; ++slot){
      const int nt = wave + slot*8;
      if (nt < 15){
        #pragma unroll
        for (int ct = 0; ct < 8; ++ct){
          f32x4 acc = {0.f,0.f,0.f,0.f};
          #pragma unroll
          for (int k = 0; k < 8; ++k){
            bf16x8 xf = ld_frag_lds(xl, swz(ct*16 + col, k*32 + hi*8));
            acc = MFMA(xf, __builtin_bit_cast(bf16x8, attf[slot][k]), acc);
          }
          ylo[slot][half*8 + ct] = (unsigned int)f2bf(acc[0]) | ((unsigned int)f2bf(acc[1]) << 16);
          yhi[slot][half*8 + ct] = (unsigned int)f2bf(acc[2]) | ((unsigned int)f2bf(acc[3]) << 16);
        }
      }
    }
  }

  uint4 y1f[2][8];
  #pragma unroll
  for (int slot = 0; slot < 2; ++slot){
    const int nt = wave + slot*8;
    if (nt < 15)
      repack_frag(ylo[slot], yhi[slot], y1f[slot], lane);
  }

  #pragma unroll 1
  for (int oe = 0; oe < 16; ++oe){
    __syncthreads();
    for (int i = tid; i < 16*128; i += 512){
      int olr = i >> 7, c = (i & 127)*2;
      const float* wr = wproj + (size_t)(oe*16 + olr)*256 + c;
      *(unsigned int*)(&wl[swz(olr, c)]) =
          (unsigned int)f2bf(wr[0]) | ((unsigned int)f2bf(wr[1]) << 16);
    }
    __syncthreads();
    bf16x8 awf[8];
    #pragma unroll
    for (int k = 0; k < 8; ++k)
      awf[k] = ld_frag_lds(wl, swz(col, k*32 + hi*8));
    #pragma unroll
    for (int slot = 0; slot < 2; ++slot){
      const int nt = wave + slot*8;
      if (nt < 15){
        f32x4 y2 = {0.f,0.f,0.f,0.f};
        #pragma unroll
        for (int k = 0; k < 8; ++k)
          y2 = MFMA(awf[k], __builtin_bit_cast(bf16x8, y1f[slot][k]), y2);
        const int n = nt*16 + col;
        if (n <= 224){
          const size_t pix = hwp[n];
          #pragma unroll
          for (int jj = 0; jj < 4; ++jj){
            int o = oe*16 + hi*4 + jj;
            float xr = bf2f(xbw[(size_t)o*XBB_ROW + n]);
            out[obase + (size_t)o*57600 + pix] = y2[jj] + xr;
          }
        }
      }
    }
  }
}

// ---------------- R6-exact fallback (small ws) -------------------------------
__global__ __launch_bounds__(512,4) void k_attn_s(
    const float* __restrict__ x, const float* __restrict__ wproj,
    const unsigned short* __restrict__ qkws, float* __restrict__ out)
{
  __shared__ __align__(16) unsigned short S[40320 + 480];
  unsigned short* kl = S;
  unsigned short* xl = S;
  unsigned short* wl = S + 32768;
  unsigned int*  hwp = (unsigned int*)(S + 40320);
  const int wg = blockIdx.x;
  const int b  = wg >> 8;
  const int th = (wg >> 4) & 15, tw = wg & 15;
  const int h0 = th*15, w0 = tw*15;
  const int tid = threadIdx.x;
  const int lane = tid & 63, wave = tid >> 6;
  const int col  = lane & 15, hi = lane >> 4;
  const size_t xbase = (size_t)b * 256 * 57600;
  const unsigned short* qkb = qkws + (size_t)b * 57600 * QK_ROW;

  if (tid < 240){
    int ms = tid <= 224 ? tid : 224;
    hwp[tid] = (unsigned int)((h0 + ms/15)*240 + w0 + ms%15);
  }
  __syncthreads();

  for (int i = tid; i < 240*20; i += 512){
    int m = i / 20, eb = i - m*20;
    *(uint4*)(&kl[m*KL_STRIDE + eb*8]) =
        *(const uint4*)(qkb + (size_t)hwp[m]*QK_ROW + 160 + eb*8);
  }
  __syncthreads();

  uint4 attf[2][8];
  #pragma unroll
  for (int slot = 0; slot < 2; ++slot){
    const int nt = wave + slot*8;
    if (nt < 15){
      const int n  = nt*16 + col;
      const int na = n <= 224 ? n : 224;
      const unsigned short* qrow = qkb + (size_t)hwp[na]*QK_ROW;
      bf16x8 qf[5];
      #pragma unroll
      for (int c = 0; c < 5; ++c)
        qf[c] = ld_frag_b(qrow + c*32 + hi*8);
      f32x4 at[15];
      #pragma unroll
      for (int T = 0; T < 15; ++T){
        f32x4 acc = {0.f,0.f,0.f,0.f};
        #pragma unroll
        for (int c = 0; c < 5; ++c){
          bf16x8 kf = ld_frag_lds(kl, (T*16 + col)*KL_STRIDE + c*32 + hi*8);
          acc = MFMA(kf, qf[c], acc);
        }
        at[T] = acc;
      }
      const float sc = 0.12022458674074695f;
      float M = -3.0e38f;
      #pragma unroll
      for (int T = 0; T < 15; ++T){
        #pragma unroll
        for (int jj = 0; jj < 4; ++jj){
          int m = T*16 + hi*4 + jj;
          if (m <= 224) M = fmaxf(M, at[T][jj]*sc);
        }
      }
      M = fmaxf(M, __shfl_xor(M, 16));
      M = fmaxf(M, __shfl_xor(M, 32));
      float Ssum = 0.f;
      #pragma unroll
      for (int T = 0; T < 15; ++T){
        #pragma unroll
        for (int jj = 0; jj < 4; ++jj){
          int m = T*16 + hi*4 + jj;
          float v = (m <= 224) ? exp2f(at[T][jj]*sc - M) : 0.f;
          at[T][jj] = v; Ssum += v;
        }
      }
      Ssum += __shfl_xor(Ssum, 16);
      Ssum += __shfl_xor(Ssum, 32);
      const float inv = 1.0f / Ssum;
      unsigned int plo[16], phi[16];
      #pragma unroll
      for (int T = 0; T < 15; ++T){
        plo[T] = (unsigned int)f2bf(at[T][0]*inv) | ((unsigned int)f2bf(at[T][1]*inv) << 16);
        phi[T] = (unsigned int)f2bf(at[T][2]*inv) | ((unsigned int)f2bf(at[T][3]*inv) << 16);
      }
      plo[15] = 0u; phi[15] = 0u;
      repack_frag(plo, phi, attf[slot], lane);
    }
  }

  unsigned int ylo[2][16], yhi[2][16];
  #pragma unroll
  for (int half = 0; half < 2; ++half){
    __syncthreads();
    for (int i = tid; i < 128*128; i += 512){
      int c = i >> 7, m = (i & 127)*2;
      int m0 = m <= 224 ? m : 224;
      float f0 = (m     <= 224) ? x[xbase + (size_t)(half*128 + c)*57600 + hwp[m0]]   : 0.f;
      float f1 = (m + 1 <= 224) ? x[xbase + (size_t)(half*128 + c)*57600 + hwp[m0+1]] : 0.f;
      *(unsigned int*)(&xl[swz(c, m)]) =
          (unsigned int)f2bf(f0) | ((unsigned int)f2bf(f1) << 16);
    }
    __syncthreads();
    #pragma unroll
    for (int slot = 0; slot < 2; ++slot){
      const int nt = wave + slot*8;
      if (nt < 15){
        #pragma unroll
        for (int ct = 0; ct < 8; ++ct){
          f32x4 acc = {0.f,0.f,0.f,0.f};
          #pragma unroll
          for (int k = 0; k < 8; ++k){
            bf16x8 xf = ld_frag_lds(xl, swz(ct*16 + col, k*32 + hi*8));
            acc = MFMA(xf, __builtin_bit_cast(bf16x8, attf[slot][k]), acc);
          }
          ylo[slot][half*8 + ct] = (unsigned int)f2bf(acc[0]) | ((unsigned int)f2bf(acc[1]) << 16);
          yhi[slot][half*8 + ct] = (unsigned int)f2bf(acc[2]) | ((unsigned int)f2bf(acc[3]) << 16);
        }
      }
    }
  }

  uint4 y1f[2][8];
  #pragma unroll
  for (int slot = 0; slot < 2; ++slot){
    const int nt = wave + slot*8;
    if (nt < 15)
      repack_frag(ylo[slot], yhi[slot], y1f[slot], lane);
  }

  #pragma unroll 1
  for (int oe = 0; oe < 16; ++oe){
    __syncthreads();
    for (int i = tid; i < 16*128; i += 512){
      int olr = i >> 7, c = (i & 127)*2;
      const float* wr = wproj + (size_t)(oe*16 + olr)*256 + c;
      *(unsigned int*)(&wl[swz(olr, c)]) =
          (unsigned int)f2bf(wr[0]) | ((unsigned int)f2bf(wr[1]) << 16);
    }
    __syncthreads();
    bf16x8 awf[8];
    #pragma unroll
    for (int k = 0; k < 8; ++k)
      awf[k] = ld_frag_lds(wl, swz(col, k*32 + hi*8));
    #pragma unroll
    for (int slot = 0; slot < 2; ++slot){
      const int nt = wave + slot*8;
      if (nt < 15){
        f32x4 y2 = {0.f,0.f,0.f,0.f};
        #pragma unroll
        for (int k = 0; k < 8; ++k)
          y2 = MFMA(awf[k], __builtin_bit_cast(bf16x8, y1f[slot][k]), y2);
        const int n = nt*16 + col;
        if (n <= 224){
          const size_t pix = hwp[n];
          #pragma unroll
          for (int jj = 0; jj < 4; ++jj){
            int o = oe*16 + hi*4 + jj;
            const size_t idx = xbase + (size_t)o*57600 + pix;
            out[idx] = y2[jj] + x[idx];
          }
        }
      }
    }
  }
}

extern "C" void kernel_launch(void* const* d_in, const int* in_sizes, int n_in,
                              void* d_out, int out_size, void* d_ws, size_t ws_size,
                              hipStream_t stream)
{
  const float* x     = (const float*)d_in[0];
  const float* wq    = (const float*)d_in[1];
  const float* wk    = (const float*)d_in[2];
  const float* wproj = (const float*)d_in[3];
  float* out = (float*)d_out;
  (void)in_sizes; (void)n_in; (void)out_size;

  const size_t QKWS_B = (size_t)8*57600*QK_ROW*2;        // 294,912,000
  const size_t XBB_B  = (size_t)8*256*256*XBB_ROW*2;     // 251,658,240
  const size_t WQB_B  = (size_t)160*256*2;               //  81,920
  const size_t WKB_B  = (size_t)160*256*2;               //  81,920
  const size_t WPB_B  = (size_t)256*256*2;               // 131,072
  unsigned short* qkws = (unsigned short*)d_ws;

  if (ws_size >= QKWS_B + XBB_B + WQB_B + WKB_B + WPB_B){
    unsigned short* xbb = (unsigned short*)((char*)d_ws + QKWS_B);
    unsigned short* wqb = (unsigned short*)((char*)d_ws + QKWS_B + XBB_B);
    unsigned short* wkb = wqb + 160*256;
    unsigned short* wpb = wkb + 160*256;
    k_w     <<<dim3(288),  dim3(256), 0, stream>>>(wq, wk, wproj, wqb, wkb, wpb);
    k_xb    <<<dim3(4096), dim3(256), 0, stream>>>(x, xbb);
    k_qkb   <<<dim3(2048), dim3(512), 0, stream>>>(xbb, wqb, wkb, qkws);
    k_attn_b<<<dim3(2048), dim3(512), 0, stream>>>(xbb, wproj, qkws, out);
  } else if (ws_size >= QKWS_B + XBB_B){
    unsigned short* xbb = (unsigned short*)((char*)d_ws + QKWS_B);
    k_xb    <<<dim3(4096), dim3(256), 0, stream>>>(x, xbb);
    k_qk    <<<dim3(3600), dim3(512), 0, stream>>>(x, wq, wk, qkws);
    k_attn_b<<<dim3(2048), dim3(512), 0, stream>>>(xbb, wproj, qkws, out);
  } else {
    k_qk    <<<dim3(3600), dim3(512), 0, stream>>>(x, wq, wk, qkws);
    k_attn_s<<<dim3(2048), dim3(512), 0, stream>>>(x, wproj, qkws, out);
  }
}

// Round 11
// 954.488 us; speedup vs baseline: 1.3387x; 1.0891x over previous
//
#include <hip/hip_runtime.h>

// PNLM: patch (15x15) non-local attention + projection + residual.
// k_w   : bf16 weight copies (wqb/wkb zero-padded [160][256], wpb[256][256]).
// k_xb  : x (raster fp32) -> xbb[blk][c][240] bf16 (proven).
// k_qkb : per-block QK projections from xbb; af[2][8] both halves up front ->
//         single 5-round weight loop (stages halved vs R10).
// k_attn_b: K in LDS, att^T, lane-local softmax, PV from xbb, P4 projection in
//         8x32-row rounds from bf16 wpb (no fp32 convert), bf16 residual.
// k_qk/k_attn_s: small-ws fallback (R6-exact, proven).
// NO v_cvt_pk_bf16_f32 inline asm (convicted of NaN R2/R3/R5).

typedef __bf16 bf16x8 __attribute__((ext_vector_type(8)));
typedef float  f32x4  __attribute__((ext_vector_type(4)));

#define MFMA(a,b,c) __builtin_amdgcn_mfma_f32_16x16x32_bf16((a),(b),(c),0,0,0)

#define QK_ROW 320            // Q cols 0..159 (144+ zero), K cols 160..319 (144+ zero)
#define KL_STRIDE 168         // kl row stride in ushorts (336B: 16B-aligned)
#define XBB_ROW 240           // xbb row length in ushorts (480B)

__device__ __forceinline__ unsigned short f2bf(float f){
  union { float f; unsigned int u; } v; v.f = f;
  unsigned int r = v.u + 0x7FFFu + ((v.u >> 16) & 1u);   // RNE
  return (unsigned short)(r >> 16);
}
__device__ __forceinline__ float bf2f(unsigned short u){
  union { unsigned int u; float f; } v; v.u = ((unsigned int)u) << 16;
  return v.f;
}
// 16B-block XOR swizzle for [rows][256] bf16 tiles.
__device__ __forceinline__ int swz(int row, int col){
  return row*256 + ((((col >> 3) ^ (row & 7)) << 3) | (col & 7));
}
// Transpose-friendly swizzle (write per-element column scatter, read 8-contig).
__device__ __forceinline__ int swzC(int row, int col){
  return row*256 + (col ^ ((((row >> 3) ^ row) & 7) << 3));
}
__device__ __forceinline__ bf16x8 ld_frag_lds(const unsigned short* p, int idx){
  uint4 v = *(const uint4*)(p + idx);
  return __builtin_bit_cast(bf16x8, v);
}
__device__ __forceinline__ bf16x8 ld_frag_b(const void* p){
  uint4 v = *(const uint4*)(p);
  return __builtin_bit_cast(bf16x8, v);
}

__device__ __forceinline__ void repack_frag(const unsigned int* plo, const unsigned int* phi,
                                            uint4* outf, int lane){
  const int nn = lane & 15, hh = lane >> 4;
  const int sla = nn + 32*(hh & 1);
  const int slb = sla + 16;
  const bool up = hh >= 2;
  #pragma unroll
  for (int k = 0; k < 8; ++k){
    unsigned int a0 = (unsigned int)__shfl((int)plo[2*k],   sla);
    unsigned int a1 = (unsigned int)__shfl((int)plo[2*k+1], sla);
    unsigned int b0 = (unsigned int)__shfl((int)phi[2*k],   sla);
    unsigned int b1 = (unsigned int)__shfl((int)phi[2*k+1], sla);
    unsigned int c0 = (unsigned int)__shfl((int)plo[2*k],   slb);
    unsigned int c1 = (unsigned int)__shfl((int)plo[2*k+1], slb);
    unsigned int d0 = (unsigned int)__shfl((int)phi[2*k],   slb);
    unsigned int d1 = (unsigned int)__shfl((int)phi[2*k+1], slb);
    outf[k] = make_uint4(up?a1:a0, up?b1:b0, up?c1:c0, up?d1:d0);
  }
}

// ---------------- kernel W: bf16 weight copies -------------------------------
__global__ __launch_bounds__(256) void k_w(
    const float* __restrict__ wq, const float* __restrict__ wk,
    const float* __restrict__ wproj,
    unsigned short* __restrict__ wqb, unsigned short* __restrict__ wkb,
    unsigned short* __restrict__ wpb)
{
  int i = blockIdx.x*256 + threadIdx.x;             // pair index, grid 288
  if (i < 20480){
    int e = i >> 7, c = (i & 127)*2;
    unsigned int v = 0;
    if (e < 144) v = (unsigned int)f2bf(wq[e*256+c]) | ((unsigned int)f2bf(wq[e*256+c+1]) << 16);
    *(unsigned int*)(wqb + (size_t)i*2) = v;
  } else if (i < 40960){
    int j = i - 20480;
    int e = j >> 7, c = (j & 127)*2;
    unsigned int v = 0;
    if (e < 144) v = (unsigned int)f2bf(wk[e*256+c]) | ((unsigned int)f2bf(wk[e*256+c+1]) << 16);
    *(unsigned int*)(wkb + (size_t)j*2) = v;
  } else if (i < 73728){
    int l = i - 40960;
    int o = l >> 7, c = (l & 127)*2;
    *(unsigned int*)(wpb + (size_t)l*2) =
        (unsigned int)f2bf(wproj[o*256+c]) | ((unsigned int)f2bf(wproj[o*256+c+1]) << 16);
  }
}

// ---------------- kernel 0: x -> xbb blocked transpose (frozen) --------------
__global__ __launch_bounds__(256) void k_xb(
    const float* __restrict__ x, unsigned short* __restrict__ xbb)
{
  __shared__ unsigned short xs[8*15*240];
  const int wg = blockIdx.x;                // b(8) x th(16) x cg(32)
  const int cg = wg & 31;
  const int th = (wg >> 5) & 15;
  const int b  = wg >> 9;
  const int tid = threadIdx.x;

  const float* xb = x + ((size_t)b*256 + cg*8)*57600 + th*15*240;
  for (int i = tid; i < 8*15*120; i += 256){
    int c = i / 1800;
    int rem = i - c*1800;
    int r = rem / 120, p2 = rem - r*120;
    float2 v = *(const float2*)(xb + (size_t)c*57600 + r*240 + p2*2);
    *(unsigned int*)(&xs[(c*15 + r)*240 + p2*2]) =
        (unsigned int)f2bf(v.x) | ((unsigned int)f2bf(v.y) << 16);
  }
  __syncthreads();

  for (int i = tid; i < 8*16*30; i += 256){
    int c = i / 480;
    int rem = i - c*480;
    int tw = rem / 30, ch = rem - tw*30;
    union { unsigned short u16[8]; uint4 u4; } pk;
    #pragma unroll
    for (int j = 0; j < 8; ++j){
      int m = ch*8 + j;
      int r = m / 15, s = m - r*15;
      pk.u16[j] = (m <= 224) ? xs[(c*15 + r)*240 + tw*15 + s] : (unsigned short)0;
    }
    *(uint4*)(xbb + ((size_t)(b*256 + th*16 + tw)*256 + cg*8 + c)*XBB_ROW + ch*8) = pk.u4;
  }
}

// ---------------- kernel 1b: per-block QK projections ------------------------
__global__ __launch_bounds__(512) void k_qkb(
    const unsigned short* __restrict__ xbb,
    const unsigned short* __restrict__ wqb, const unsigned short* __restrict__ wkb,
    unsigned short* __restrict__ qkws)
{
  // xt[128][256] swzC (65,536B); wqs/wks alias xt after both halves' af loaded.
  __shared__ __align__(16) unsigned short S[32768];
  unsigned short* xt  = S;
  unsigned short* wqs = S;
  unsigned short* wks = S + 8192;
  const int wg = blockIdx.x;
  const int b  = wg >> 8;
  const int th = (wg >> 4) & 15, tw = wg & 15;
  const int h0 = th*15, w0 = tw*15;
  const int tid = threadIdx.x;
  const int lane = tid & 63, wave = tid >> 6;
  const int col  = lane & 15, hi = lane >> 4;
  const unsigned short* xbw = xbb + (size_t)wg * (256*XBB_ROW);

  bf16x8 af[2][8];                       // both m-halves' A-frags up front
  #pragma unroll 1
  for (int half = 0; half < 2; ++half){
    if (half) __syncthreads();           // prev half's af loads done
    for (int i = tid; i < 256*16; i += 512){
      int c = i >> 4, m8 = i & 15;
      int m = half*128 + m8*8;
      if (m + 8 <= 240){
        uint4 v = *(const uint4*)(xbw + (size_t)c*XBB_ROW + m);
        const unsigned short* pv = (const unsigned short*)&v;
        #pragma unroll
        for (int j = 0; j < 8; ++j)
          xt[swzC(m8*8 + j, c)] = pv[j];
      }
    }
    __syncthreads();
    const int rloc = wave*16 + col;
    if (half == 0){
      #pragma unroll
      for (int k = 0; k < 8; ++k)
        af[0][k] = ld_frag_lds(xt, swzC(rloc, k*32 + hi*8));
    } else {
      #pragma unroll
      for (int k = 0; k < 8; ++k)
        af[1][k] = ld_frag_lds(xt, swzC(rloc, k*32 + hi*8));
    }
  }
  __syncthreads();                       // xt fully consumed -> weights

  #pragma unroll 1
  for (int eg = 0; eg < 5; ++eg){
    if (eg) __syncthreads();
    for (int i = tid; i < 32*32; i += 512){
      int e_l = i >> 5, c8 = (i & 31)*8;
      size_t off = (size_t)(eg*32 + e_l)*256 + c8;
      *(uint4*)(&wqs[swz(e_l, c8)]) = *(const uint4*)(wqb + off);
      *(uint4*)(&wks[swz(e_l, c8)]) = *(const uint4*)(wkb + off);
    }
    __syncthreads();
    #pragma unroll
    for (int h2 = 0; h2 < 2; ++h2){
      const int t = h2*8 + wave;
      if (t < 15){
        #pragma unroll
        for (int et = 0; et < 2; ++et){
          f32x4 aq = {0.f,0.f,0.f,0.f}, ak = {0.f,0.f,0.f,0.f};
          const int el = et*16 + col;
          #pragma unroll
          for (int k = 0; k < 8; ++k){
            int idx = swz(el, k*32 + hi*8);
            bf16x8 bq = ld_frag_lds(wqs, idx);
            bf16x8 bk = ld_frag_lds(wks, idx);
            aq = MFMA(af[h2][k], bq, aq);
            ak = MFMA(af[h2][k], bk, ak);
          }
          const int e_out = eg*32 + et*16 + col;
          #pragma unroll
          for (int jj = 0; jj < 4; ++jj){
            int m_px = t*16 + hi*4 + jj;
            if (m_px <= 224){
              int hw = (h0 + m_px/15)*240 + w0 + m_px%15;
              size_t row = ((size_t)b*57600 + hw)*QK_ROW;
              qkws[row + e_out]       = f2bf(aq[jj]);
              qkws[row + 160 + e_out] = f2bf(ak[jj]);
            }
          }
        }
      }
    }
  }
}

// ---------------- kernel 2 (big ws): attention + PV + proj + residual --------
__global__ __launch_bounds__(512,4) void k_attn_b(
    const unsigned short* __restrict__ xbb, const unsigned short* __restrict__ wpb,
    const unsigned short* __restrict__ qkws, float* __restrict__ out)
{
  // S (81,920 B exactly -> 2 WG/CU):
  //   P0/P1: kl[240][168] (ush 0..40,320) | hwp (ush 40,320..40,800)
  //   P2+  : xl[128][256] (ush 0..32,768) | wl[32][256] (ush 32,768..40,960)
  __shared__ __align__(16) unsigned short S[40960];
  unsigned short* kl = S;
  unsigned short* xl = S;
  unsigned short* wl = S + 32768;
  unsigned int*  hwp = (unsigned int*)(S + 40320);
  const int wg = blockIdx.x;
  const int b  = wg >> 8;
  const int th = (wg >> 4) & 15, tw = wg & 15;
  const int h0 = th*15, w0 = tw*15;
  const int tid = threadIdx.x;
  const int lane = tid & 63, wave = tid >> 6;
  const int col  = lane & 15, hi = lane >> 4;
  const size_t obase = (size_t)b * 256 * 57600;
  const unsigned short* qkb = qkws + (size_t)b * 57600 * QK_ROW;
  const unsigned short* xbw = xbb + (size_t)wg * (256*XBB_ROW);

  if (tid < 240){
    int ms = tid <= 224 ? tid : 224;
    hwp[tid] = (unsigned int)((h0 + ms/15)*240 + w0 + ms%15);
  }
  __syncthreads();

  // ---- P0: stage K rows into kl (coalesced) ----
  for (int i = tid; i < 240*20; i += 512){
    int m = i / 20, eb = i - m*20;
    *(uint4*)(&kl[m*KL_STRIDE + eb*8]) =
        *(const uint4*)(qkb + (size_t)hwp[m]*QK_ROW + 160 + eb*8);
  }
  __syncthreads();

  // ---- P1: att^T strips + lane-local softmax + register repack ----
  uint4 attf[2][8];
  #pragma unroll
  for (int slot = 0; slot < 2; ++slot){
    const int nt = wave + slot*8;
    if (nt < 15){
      const int n  = nt*16 + col;
      const int na = n <= 224 ? n : 224;
      const unsigned short* qrow = qkb + (size_t)hwp[na]*QK_ROW;
      bf16x8 qf[5];
      #pragma unroll
      for (int c = 0; c < 5; ++c)
        qf[c] = ld_frag_b(qrow + c*32 + hi*8);
      f32x4 at[15];
      #pragma unroll
      for (int T = 0; T < 15; ++T){
        f32x4 acc = {0.f,0.f,0.f,0.f};
        #pragma unroll
        for (int c = 0; c < 5; ++c){
          bf16x8 kf = ld_frag_lds(kl, (T*16 + col)*KL_STRIDE + c*32 + hi*8);
          acc = MFMA(kf, qf[c], acc);             // att^T[m][n]
        }
        at[T] = acc;
      }
      const float sc = 0.12022458674074695f;      // log2(e)/12
      float M = -3.0e38f;
      #pragma unroll
      for (int T = 0; T < 15; ++T){
        #pragma unroll
        for (int jj = 0; jj < 4; ++jj){
          int m = T*16 + hi*4 + jj;
          if (m <= 224) M = fmaxf(M, at[T][jj]*sc);
        }
      }
      M = fmaxf(M, __shfl_xor(M, 16));
      M = fmaxf(M, __shfl_xor(M, 32));
      float Ssum = 0.f;
      #pragma unroll
      for (int T = 0; T < 15; ++T){
        #pragma unroll
        for (int jj = 0; jj < 4; ++jj){
          int m = T*16 + hi*4 + jj;
          float v = (m <= 224) ? exp2f(at[T][jj]*sc - M) : 0.f;
          at[T][jj] = v; Ssum += v;
        }
      }
      Ssum += __shfl_xor(Ssum, 16);
      Ssum += __shfl_xor(Ssum, 32);
      const float inv = 1.0f / Ssum;
      unsigned int plo[16], phi[16];
      #pragma unroll
      for (int T = 0; T < 15; ++T){
        plo[T] = (unsigned int)f2bf(at[T][0]*inv) | ((unsigned int)f2bf(at[T][1]*inv) << 16);
        phi[T] = (unsigned int)f2bf(at[T][2]*inv) | ((unsigned int)f2bf(at[T][3]*inv) << 16);
      }
      plo[15] = 0u; phi[15] = 0u;
      repack_frag(plo, phi, attf[slot], lane);
    }
  }

  // hoist per-slot store coords from hwp (wl will overwrite it in P4)
  int pixs[2];
  #pragma unroll
  for (int slot = 0; slot < 2; ++slot){
    const int n = (wave + slot*8)*16 + col;
    pixs[slot] = (n <= 224) ? (int)hwp[n] : -1;
  }

  // ---- P2/P3: X from xbb into xl; PV partials bf16 ----
  unsigned int ylo[2][16], yhi[2][16];
  #pragma unroll
  for (int half = 0; half < 2; ++half){
    __syncthreads();
    for (int i = tid; i < 128*32; i += 512){
      int c = i >> 5, m8 = i & 31;
      uint4 v = make_uint4(0u,0u,0u,0u);
      if (m8 < 30)
        v = *(const uint4*)(xbw + (size_t)(half*128 + c)*XBB_ROW + m8*8);
      *(uint4*)(&xl[swz(c, m8*8)]) = v;
    }
    __syncthreads();
    #pragma unroll
    for (int slot = 0; slot < 2; ++slot){
      const int nt = wave + slot*8;
      if (nt < 15){
        #pragma unroll
        for (int ct = 0; ct < 8; ++ct){
          f32x4 acc = {0.f,0.f,0.f,0.f};
          #pragma unroll
          for (int k = 0; k < 8; ++k){
            bf16x8 xf = ld_frag_lds(xl, swz(ct*16 + col, k*32 + hi*8));
            acc = MFMA(xf, __builtin_bit_cast(bf16x8, attf[slot][k]), acc);
          }
          ylo[slot][half*8 + ct] = (unsigned int)f2bf(acc[0]) | ((unsigned int)f2bf(acc[1]) << 16);
          yhi[slot][half*8 + ct] = (unsigned int)f2bf(acc[2]) | ((unsigned int)f2bf(acc[3]) << 16);
        }
      }
    }
  }

  uint4 y1f[2][8];
  #pragma unroll
  for (int slot = 0; slot < 2; ++slot){
    const int nt = wave + slot*8;
    if (nt < 15)
      repack_frag(ylo[slot], yhi[slot], y1f[slot], lane);
  }

  // ---- P4: projection from bf16 wpb, 8 rounds x 32 rows + residual ----
  #pragma unroll 1
  for (int oe = 0; oe < 8; ++oe){
    __syncthreads();                          // prev wl readers / PV readers done
    for (int i = tid; i < 32*32; i += 512){
      int olr = i >> 5, c8 = (i & 31)*8;
      *(uint4*)(&wl[swz(olr, c8)]) =
          *(const uint4*)(wpb + (size_t)(oe*32 + olr)*256 + c8);
    }
    __syncthreads();
    #pragma unroll
    for (int ot = 0; ot < 2; ++ot){
      bf16x8 awf[8];
      const int olr = ot*16 + col;
      #pragma unroll
      for (int k = 0; k < 8; ++k)
        awf[k] = ld_frag_lds(wl, swz(olr, k*32 + hi*8));
      #pragma unroll
      for (int slot = 0; slot < 2; ++slot){
        const int nt = wave + slot*8;
        if (nt < 15){
          f32x4 y2 = {0.f,0.f,0.f,0.f};
          #pragma unroll
          for (int k = 0; k < 8; ++k)
            y2 = MFMA(awf[k], __builtin_bit_cast(bf16x8, y1f[slot][k]), y2);
          const int n = nt*16 + col;
          if (n <= 224){
            const size_t pix = (size_t)pixs[slot];
            #pragma unroll
            for (int jj = 0; jj < 4; ++jj){
              int o = oe*32 + ot*16 + hi*4 + jj;
              float xr = bf2f(xbw[(size_t)o*XBB_ROW + n]);
              out[obase + (size_t)o*57600 + pix] = y2[jj] + xr;
            }
          }
        }
      }
    }
  }
}

// ---------------- small-ws fallback: R6-exact --------------------------------
__global__ __launch_bounds__(512) void k_qk(
    const float* __restrict__ x, const float* __restrict__ wq,
    const float* __restrict__ wk,
    unsigned short* __restrict__ qkws)
{
  __shared__ __align__(16) unsigned short S[32768];
  unsigned short* xt  = S;
  unsigned short* wqs = S;
  unsigned short* wks = S + 8192;
  const int wg  = blockIdx.x;
  const int b   = wg / 450;
  const int hw0 = (wg % 450) * 128;
  const int tid = threadIdx.x;
  const int lane = tid & 63, wave = tid >> 6;
  const int col  = lane & 15, hi = lane >> 4;

  {
    const float* xb = x + (size_t)b * 256 * 57600 + hw0;
    const int hw_l = tid & 127;
    #pragma unroll 4
    for (int i = 0; i < 32; ++i){
      int c = ((tid >> 7) * 32 + i) * 2;
      float f0 = xb[(size_t)c     * 57600 + hw_l];
      float f1 = xb[(size_t)(c+1) * 57600 + hw_l];
      *(unsigned int*)(&xt[swz(hw_l, c)]) =
          (unsigned int)f2bf(f0) | ((unsigned int)f2bf(f1) << 16);
    }
  }
  __syncthreads();

  bf16x8 af[8];
  const int arow = wave*16 + col;
  #pragma unroll
  for (int k = 0; k < 8; ++k)
    af[k] = ld_frag_lds(xt, swz(arow, k*32 + hi*8));

  const size_t orow_base = (size_t)b*57600 + hw0 + wave*16;

  for (int eg = 0; eg < 5; ++eg){
    __syncthreads();
    for (int i = 0; i < 8; ++i){
      int idx = tid + i*512;
      int e_l = idx >> 7, c = (idx & 127) * 2;
      int e = eg*32 + e_l;
      float2 vq = make_float2(0.f,0.f), vk = make_float2(0.f,0.f);
      if (e < 144){
        vq = *(const float2*)(wq + (size_t)e*256 + c);
        vk = *(const float2*)(wk + (size_t)e*256 + c);
      }
      *(unsigned int*)(&wqs[swz(e_l, c)]) =
          (unsigned int)f2bf(vq.x) | ((unsigned int)f2bf(vq.y) << 16);
      *(unsigned int*)(&wks[swz(e_l, c)]) =
          (unsigned int)f2bf(vk.x) | ((unsigned int)f2bf(vk.y) << 16);
    }
    __syncthreads();
    #pragma unroll
    for (int etl = 0; etl < 2; ++etl){
      f32x4 aq = {0.f,0.f,0.f,0.f}, ak = {0.f,0.f,0.f,0.f};
      const int el = etl*16 + col;
      #pragma unroll
      for (int k = 0; k < 8; ++k){
        int idx = swz(el, k*32 + hi*8);
        bf16x8 bq = ld_frag_lds(wqs, idx);
        bf16x8 bk = ld_frag_lds(wks, idx);
        aq = MFMA(af[k], bq, aq);
        ak = MFMA(af[k], bk, ak);
      }
      const int e_out = eg*32 + etl*16 + col;
      #pragma unroll
      for (int jj = 0; jj < 4; ++jj){
        size_t row = orow_base + hi*4 + jj;
        qkws[row*QK_ROW + e_out]       = f2bf(aq[jj]);
        qkws[row*QK_ROW + 160 + e_out] = f2bf(ak[jj]);
      }
    }
  }
}

__global__ __launch_bounds__(512,4) void k_attn_s(
    const float* __restrict__ x, const float* __restrict__ wproj,
    const unsigned short* __restrict__ qkws, float* __restrict__ out)
{
  __shared__ __align__(16) unsigned short S[40320 + 480];
  unsigned short* kl = S;
  unsigned short* xl = S;
  unsigned short* wl = S + 32768;
  unsigned int*  hwp = (unsigned int*)(S + 40320);
  const int wg = blockIdx.x;
  const int b  = wg >> 8;
  const int th = (wg >> 4) & 15, tw = wg & 15;
  const int h0 = th*15, w0 = tw*15;
  const int tid = threadIdx.x;
  const int lane = tid & 63, wave = tid >> 6;
  const int col  = lane & 15, hi = lane >> 4;
  const size_t xbase = (size_t)b * 256 * 57600;
  const unsigned short* qkb = qkws + (size_t)b * 57600 * QK_ROW;

  if (tid < 240){
    int ms = tid <= 224 ? tid : 224;
    hwp[tid] = (unsigned int)((h0 + ms/15)*240 + w0 + ms%15);
  }
  __syncthreads();

  for (int i = tid; i < 240*20; i += 512){
    int m = i / 20, eb = i - m*20;
    *(uint4*)(&kl[m*KL_STRIDE + eb*8]) =
        *(const uint4*)(qkb + (size_t)hwp[m]*QK_ROW + 160 + eb*8);
  }
  __syncthreads();

  uint4 attf[2][8];
  #pragma unroll
  for (int slot = 0; slot < 2; ++slot){
    const int nt = wave + slot*8;
    if (nt < 15){
      const int n  = nt*16 + col;
      const int na = n <= 224 ? n : 224;
      const unsigned short* qrow = qkb + (size_t)hwp[na]*QK_ROW;
      bf16x8 qf[5];
      #pragma unroll
      for (int c = 0; c < 5; ++c)
        qf[c] = ld_frag_b(qrow + c*32 + hi*8);
      f32x4 at[15];
      #pragma unroll
      for (int T = 0; T < 15; ++T){
        f32x4 acc = {0.f,0.f,0.f,0.f};
        #pragma unroll
        for (int c = 0; c < 5; ++c){
          bf16x8 kf = ld_frag_lds(kl, (T*16 + col)*KL_STRIDE + c*32 + hi*8);
          acc = MFMA(kf, qf[c], acc);
        }
        at[T] = acc;
      }
      const float sc = 0.12022458674074695f;
      float M = -3.0e38f;
      #pragma unroll
      for (int T = 0; T < 15; ++T){
        #pragma unroll
        for (int jj = 0; jj < 4; ++jj){
          int m = T*16 + hi*4 + jj;
          if (m <= 224) M = fmaxf(M, at[T][jj]*sc);
        }
      }
      M = fmaxf(M, __shfl_xor(M, 16));
      M = fmaxf(M, __shfl_xor(M, 32));
      float Ssum = 0.f;
      #pragma unroll
      for (int T = 0; T < 15; ++T){
        #pragma unroll
        for (int jj = 0; jj < 4; ++jj){
          int m = T*16 + hi*4 + jj;
          float v = (m <= 224) ? exp2f(at[T][jj]*sc - M) : 0.f;
          at[T][jj] = v; Ssum += v;
        }
      }
      Ssum += __shfl_xor(Ssum, 16);
      Ssum += __shfl_xor(Ssum, 32);
      const float inv = 1.0f / Ssum;
      unsigned int plo[16], phi[16];
      #pragma unroll
      for (int T = 0; T < 15; ++T){
        plo[T] = (unsigned int)f2bf(at[T][0]*inv) | ((unsigned int)f2bf(at[T][1]*inv) << 16);
        phi[T] = (unsigned int)f2bf(at[T][2]*inv) | ((unsigned int)f2bf(at[T][3]*inv) << 16);
      }
      plo[15] = 0u; phi[15] = 0u;
      repack_frag(plo, phi, attf[slot], lane);
    }
  }

  unsigned int ylo[2][16], yhi[2][16];
  #pragma unroll
  for (int half = 0; half < 2; ++half){
    __syncthreads();
    for (int i = tid; i < 128*128; i += 512){
      int c = i >> 7, m = (i & 127)*2;
      int m0 = m <= 224 ? m : 224;
      float f0 = (m     <= 224) ? x[xbase + (size_t)(half*128 + c)*57600 + hwp[m0]]   : 0.f;
      float f1 = (m + 1 <= 224) ? x[xbase + (size_t)(half*128 + c)*57600 + hwp[m0+1]] : 0.f;
      *(unsigned int*)(&xl[swz(c, m)]) =
          (unsigned int)f2bf(f0) | ((unsigned int)f2bf(f1) << 16);
    }
    __syncthreads();
    #pragma unroll
    for (int slot = 0; slot < 2; ++slot){
      const int nt = wave + slot*8;
      if (nt < 15){
        #pragma unroll
        for (int ct = 0; ct < 8; ++ct){
          f32x4 acc = {0.f,0.f,0.f,0.f};
          #pragma unroll
          for (int k = 0; k < 8; ++k){
            bf16x8 xf = ld_frag_lds(xl, swz(ct*16 + col, k*32 + hi*8));
            acc = MFMA(xf, __builtin_bit_cast(bf16x8, attf[slot][k]), acc);
          }
          ylo[slot][half*8 + ct] = (unsigned int)f2bf(acc[0]) | ((unsigned int)f2bf(acc[1]) << 16);
          yhi[slot][half*8 + ct] = (unsigned int)f2bf(acc[2]) | ((unsigned int)f2bf(acc[3]) << 16);
        }
      }
    }
  }

  uint4 y1f[2][8];
  #pragma unroll
  for (int slot = 0; slot < 2; ++slot){
    const int nt = wave + slot*8;
    if (nt < 15)
      repack_frag(ylo[slot], yhi[slot], y1f[slot], lane);
  }

  #pragma unroll 1
  for (int oe = 0; oe < 16; ++oe){
    __syncthreads();
    for (int i = tid; i < 16*128; i += 512){
      int olr = i >> 7, c = (i & 127)*2;
      const float* wr = wproj + (size_t)(oe*16 + olr)*256 + c;
      *(unsigned int*)(&wl[swz(olr, c)]) =
          (unsigned int)f2bf(wr[0]) | ((unsigned int)f2bf(wr[1]) << 16);
    }
    __syncthreads();
    bf16x8 awf[8];
    #pragma unroll
    for (int k = 0; k < 8; ++k)
      awf[k] = ld_frag_lds(wl, swz(col, k*32 + hi*8));
    #pragma unroll
    for (int slot = 0; slot < 2; ++slot){
      const int nt = wave + slot*8;
      if (nt < 15){
        f32x4 y2 = {0.f,0.f,0.f,0.f};
        #pragma unroll
        for (int k = 0; k < 8; ++k)
          y2 = MFMA(awf[k], __builtin_bit_cast(bf16x8, y1f[slot][k]), y2);
        const int n = nt*16 + col;
        if (n <= 224){
          const size_t pix = hwp[n];
          #pragma unroll
          for (int jj = 0; jj < 4; ++jj){
            int o = oe*16 + hi*4 + jj;
            const size_t idx = xbase + (size_t)o*57600 + pix;
            out[idx] = y2[jj] + x[idx];
          }
        }
      }
    }
  }
}

extern "C" void kernel_launch(void* const* d_in, const int* in_sizes, int n_in,
                              void* d_out, int out_size, void* d_ws, size_t ws_size,
                              hipStream_t stream)
{
  const float* x     = (const float*)d_in[0];
  const float* wq    = (const float*)d_in[1];
  const float* wk    = (const float*)d_in[2];
  const float* wproj = (const float*)d_in[3];
  float* out = (float*)d_out;
  (void)in_sizes; (void)n_in; (void)out_size;

  const size_t QKWS_B = (size_t)8*57600*QK_ROW*2;        // 294,912,000
  const size_t XBB_B  = (size_t)8*256*256*XBB_ROW*2;     // 251,658,240
  const size_t WB_ALL = (size_t)(160*256 + 160*256 + 256*256)*2;  // 294,912
  unsigned short* qkws = (unsigned short*)d_ws;

  if (ws_size >= QKWS_B + XBB_B + WB_ALL){                // confirmed fits (R10)
    unsigned short* xbb = (unsigned short*)((char*)d_ws + QKWS_B);
    unsigned short* wqb = (unsigned short*)((char*)d_ws + QKWS_B + XBB_B);
    unsigned short* wkb = wqb + 160*256;
    unsigned short* wpb = wkb + 160*256;
    k_w     <<<dim3(288),  dim3(256), 0, stream>>>(wq, wk, wproj, wqb, wkb, wpb);
    k_xb    <<<dim3(4096), dim3(256), 0, stream>>>(x, xbb);
    k_qkb   <<<dim3(2048), dim3(512), 0, stream>>>(xbb, wqb, wkb, qkws);
    k_attn_b<<<dim3(2048), dim3(512), 0, stream>>>(xbb, wpb, qkws, out);
  } else {
    k_qk    <<<dim3(3600), dim3(512), 0, stream>>>(x, wq, wk, qkws);
    k_attn_s<<<dim3(2048), dim3(512), 0, stream>>>(x, wproj, qkws, out);
  }
}

// Round 12
// 946.572 us; speedup vs baseline: 1.3499x; 1.0084x over previous
//
#include <hip/hip_runtime.h>

// PNLM: patch (15x15) non-local attention + projection + residual.
// k_w    : bf16 weight copies (wqb/wkb zero-padded [160][256], wpb[256][256]).
// k_xb   : x (raster fp32) -> xbb[blk][c][240] bf16 (proven).
// k_fused: per block: phase A = QK projection (R11 k_qkb verbatim) writing the
//          block's own qkws rows; barrier (drains stores); phase B = attention
//          (R11 k_attn_b verbatim) reading those rows back L2-hot. P4 in
//          4x64-row wl rounds. LDS union 81,920B -> 2 WG/CU.
// k_qk / k_attn_s: small-ws fallback (R6-exact, proven).
// NO v_cvt_pk_bf16_f32 inline asm (convicted of NaN R2/R3/R5).

typedef __bf16 bf16x8 __attribute__((ext_vector_type(8)));
typedef float  f32x4  __attribute__((ext_vector_type(4)));

#define MFMA(a,b,c) __builtin_amdgcn_mfma_f32_16x16x32_bf16((a),(b),(c),0,0,0)

#define QK_ROW 320            // Q cols 0..159 (144+ zero), K cols 160..319 (144+ zero)
#define KL_STRIDE 168         // kl row stride in ushorts (336B: 16B-aligned)
#define XBB_ROW 240           // xbb row length in ushorts (480B)

__device__ __forceinline__ unsigned short f2bf(float f){
  union { float f; unsigned int u; } v; v.f = f;
  unsigned int r = v.u + 0x7FFFu + ((v.u >> 16) & 1u);   // RNE
  return (unsigned short)(r >> 16);
}
__device__ __forceinline__ float bf2f(unsigned short u){
  union { unsigned int u; float f; } v; v.u = ((unsigned int)u) << 16;
  return v.f;
}
// 16B-block XOR swizzle for [rows][256] bf16 tiles.
__device__ __forceinline__ int swz(int row, int col){
  return row*256 + ((((col >> 3) ^ (row & 7)) << 3) | (col & 7));
}
// Transpose-friendly swizzle (write per-element column scatter, read 8-contig).
__device__ __forceinline__ int swzC(int row, int col){
  return row*256 + (col ^ ((((row >> 3) ^ row) & 7) << 3));
}
__device__ __forceinline__ bf16x8 ld_frag_lds(const unsigned short* p, int idx){
  uint4 v = *(const uint4*)(p + idx);
  return __builtin_bit_cast(bf16x8, v);
}
__device__ __forceinline__ bf16x8 ld_frag_b(const void* p){
  uint4 v = *(const uint4*)(p);
  return __builtin_bit_cast(bf16x8, v);
}

__device__ __forceinline__ void repack_frag(const unsigned int* plo, const unsigned int* phi,
                                            uint4* outf, int lane){
  const int nn = lane & 15, hh = lane >> 4;
  const int sla = nn + 32*(hh & 1);
  const int slb = sla + 16;
  const bool up = hh >= 2;
  #pragma unroll
  for (int k = 0; k < 8; ++k){
    unsigned int a0 = (unsigned int)__shfl((int)plo[2*k],   sla);
    unsigned int a1 = (unsigned int)__shfl((int)plo[2*k+1], sla);
    unsigned int b0 = (unsigned int)__shfl((int)phi[2*k],   sla);
    unsigned int b1 = (unsigned int)__shfl((int)phi[2*k+1], sla);
    unsigned int c0 = (unsigned int)__shfl((int)plo[2*k],   slb);
    unsigned int c1 = (unsigned int)__shfl((int)plo[2*k+1], slb);
    unsigned int d0 = (unsigned int)__shfl((int)phi[2*k],   slb);
    unsigned int d1 = (unsigned int)__shfl((int)phi[2*k+1], slb);
    outf[k] = make_uint4(up?a1:a0, up?b1:b0, up?c1:c0, up?d1:d0);
  }
}

// ---------------- kernel W: bf16 weight copies -------------------------------
__global__ __launch_bounds__(256) void k_w(
    const float* __restrict__ wq, const float* __restrict__ wk,
    const float* __restrict__ wproj,
    unsigned short* __restrict__ wqb, unsigned short* __restrict__ wkb,
    unsigned short* __restrict__ wpb)
{
  int i = blockIdx.x*256 + threadIdx.x;             // pair index, grid 288
  if (i < 20480){
    int e = i >> 7, c = (i & 127)*2;
    unsigned int v = 0;
    if (e < 144) v = (unsigned int)f2bf(wq[e*256+c]) | ((unsigned int)f2bf(wq[e*256+c+1]) << 16);
    *(unsigned int*)(wqb + (size_t)i*2) = v;
  } else if (i < 40960){
    int j = i - 20480;
    int e = j >> 7, c = (j & 127)*2;
    unsigned int v = 0;
    if (e < 144) v = (unsigned int)f2bf(wk[e*256+c]) | ((unsigned int)f2bf(wk[e*256+c+1]) << 16);
    *(unsigned int*)(wkb + (size_t)j*2) = v;
  } else if (i < 73728){
    int l = i - 40960;
    int o = l >> 7, c = (l & 127)*2;
    *(unsigned int*)(wpb + (size_t)l*2) =
        (unsigned int)f2bf(wproj[o*256+c]) | ((unsigned int)f2bf(wproj[o*256+c+1]) << 16);
  }
}

// ---------------- kernel 0: x -> xbb blocked transpose (frozen) --------------
__global__ __launch_bounds__(256) void k_xb(
    const float* __restrict__ x, unsigned short* __restrict__ xbb)
{
  __shared__ unsigned short xs[8*15*240];
  const int wg = blockIdx.x;                // b(8) x th(16) x cg(32)
  const int cg = wg & 31;
  const int th = (wg >> 5) & 15;
  const int b  = wg >> 9;
  const int tid = threadIdx.x;

  const float* xb = x + ((size_t)b*256 + cg*8)*57600 + th*15*240;
  for (int i = tid; i < 8*15*120; i += 256){
    int c = i / 1800;
    int rem = i - c*1800;
    int r = rem / 120, p2 = rem - r*120;
    float2 v = *(const float2*)(xb + (size_t)c*57600 + r*240 + p2*2);
    *(unsigned int*)(&xs[(c*15 + r)*240 + p2*2]) =
        (unsigned int)f2bf(v.x) | ((unsigned int)f2bf(v.y) << 16);
  }
  __syncthreads();

  for (int i = tid; i < 8*16*30; i += 256){
    int c = i / 480;
    int rem = i - c*480;
    int tw = rem / 30, ch = rem - tw*30;
    union { unsigned short u16[8]; uint4 u4; } pk;
    #pragma unroll
    for (int j = 0; j < 8; ++j){
      int m = ch*8 + j;
      int r = m / 15, s = m - r*15;
      pk.u16[j] = (m <= 224) ? xs[(c*15 + r)*240 + tw*15 + s] : (unsigned short)0;
    }
    *(uint4*)(xbb + ((size_t)(b*256 + th*16 + tw)*256 + cg*8 + c)*XBB_ROW + ch*8) = pk.u4;
  }
}

// ---------------- fused kernel: QK projection + attention --------------------
__global__ __launch_bounds__(512,4) void k_fused(
    const unsigned short* __restrict__ xbb,
    const unsigned short* __restrict__ wqb, const unsigned short* __restrict__ wkb,
    const unsigned short* __restrict__ wpb,
    unsigned short* __restrict__ qkws, float* __restrict__ out)
{
  // LDS union (81,920B -> 2 WG/CU):
  //   phase A: xt[128][256] swzC (0..32,768 ush); wqs/wks alias xt after af.
  //   phase B: kl[240][168] (0..40,320) | xl[128][256] (0..32,768)
  //            | wl[64][256] (0..16,384, after xl dead) | hwp (40,320..40,800)
  __shared__ __align__(16) unsigned short S[40960];
  unsigned short* xt  = S;
  unsigned short* wqs = S;
  unsigned short* wks = S + 8192;
  unsigned short* kl  = S;
  unsigned short* xl  = S;
  unsigned short* wl  = S;
  unsigned int*  hwp  = (unsigned int*)(S + 40320);
  const int wg = blockIdx.x;
  const int b  = wg >> 8;
  const int th = (wg >> 4) & 15, tw = wg & 15;
  const int h0 = th*15, w0 = tw*15;
  const int tid = threadIdx.x;
  const int lane = tid & 63, wave = tid >> 6;
  const int col  = lane & 15, hi = lane >> 4;
  const size_t obase = (size_t)b * 256 * 57600;
  const unsigned short* qkb = qkws + (size_t)b * 57600 * QK_ROW;
  const unsigned short* xbw = xbb + (size_t)wg * (256*XBB_ROW);

  if (tid < 240){                               // hwp region untouched by phase A
    int ms = tid <= 224 ? tid : 224;
    hwp[tid] = (unsigned int)((h0 + ms/15)*240 + w0 + ms%15);
  }

  // ================= phase A: QK projection (R11 k_qkb) ======================
  bf16x8 af[2][8];
  #pragma unroll 1
  for (int half = 0; half < 2; ++half){
    if (half) __syncthreads();
    for (int i = tid; i < 256*16; i += 512){
      int c = i >> 4, m8 = i & 15;
      int m = half*128 + m8*8;
      if (m + 8 <= 240){
        uint4 v = *(const uint4*)(xbw + (size_t)c*XBB_ROW + m);
        const unsigned short* pv = (const unsigned short*)&v;
        #pragma unroll
        for (int j = 0; j < 8; ++j)
          xt[swzC(m8*8 + j, c)] = pv[j];
      }
    }
    __syncthreads();
    const int rloc = wave*16 + col;
    if (half == 0){
      #pragma unroll
      for (int k = 0; k < 8; ++k)
        af[0][k] = ld_frag_lds(xt, swzC(rloc, k*32 + hi*8));
    } else {
      #pragma unroll
      for (int k = 0; k < 8; ++k)
        af[1][k] = ld_frag_lds(xt, swzC(rloc, k*32 + hi*8));
    }
  }
  __syncthreads();                             // xt consumed -> weights

  #pragma unroll 1
  for (int eg = 0; eg < 5; ++eg){
    if (eg) __syncthreads();
    for (int i = tid; i < 32*32; i += 512){
      int e_l = i >> 5, c8 = (i & 31)*8;
      size_t off = (size_t)(eg*32 + e_l)*256 + c8;
      *(uint4*)(&wqs[swz(e_l, c8)]) = *(const uint4*)(wqb + off);
      *(uint4*)(&wks[swz(e_l, c8)]) = *(const uint4*)(wkb + off);
    }
    __syncthreads();
    #pragma unroll
    for (int h2 = 0; h2 < 2; ++h2){
      const int t = h2*8 + wave;
      if (t < 15){
        #pragma unroll
        for (int et = 0; et < 2; ++et){
          f32x4 aq = {0.f,0.f,0.f,0.f}, ak = {0.f,0.f,0.f,0.f};
          const int el = et*16 + col;
          #pragma unroll
          for (int k = 0; k < 8; ++k){
            int idx = swz(el, k*32 + hi*8);
            bf16x8 bq = ld_frag_lds(wqs, idx);
            bf16x8 bk = ld_frag_lds(wks, idx);
            aq = MFMA(af[h2][k], bq, aq);
            ak = MFMA(af[h2][k], bk, ak);
          }
          const int e_out = eg*32 + et*16 + col;
          #pragma unroll
          for (int jj = 0; jj < 4; ++jj){
            int m_px = t*16 + hi*4 + jj;
            if (m_px <= 224){
              int hw = (h0 + m_px/15)*240 + w0 + m_px%15;
              size_t row = ((size_t)b*57600 + hw)*QK_ROW;
              qkws[row + e_out]       = f2bf(aq[jj]);
              qkws[row + 160 + e_out] = f2bf(ak[jj]);
            }
          }
        }
      }
    }
  }
  __syncthreads();   // phase boundary: drains qkws stores; wqs/wks dead

  // ================= phase B: attention (R11 k_attn_b) =======================
  // ---- P0: stage K rows into kl (L2-hot reads of own block's rows) ----
  for (int i = tid; i < 240*20; i += 512){
    int m = i / 20, eb = i - m*20;
    *(uint4*)(&kl[m*KL_STRIDE + eb*8]) =
        *(const uint4*)(qkb + (size_t)hwp[m]*QK_ROW + 160 + eb*8);
  }
  __syncthreads();

  // ---- P1: att^T strips + lane-local softmax + register repack ----
  uint4 attf[2][8];
  #pragma unroll
  for (int slot = 0; slot < 2; ++slot){
    const int nt = wave + slot*8;
    if (nt < 15){
      const int n  = nt*16 + col;
      const int na = n <= 224 ? n : 224;
      const unsigned short* qrow = qkb + (size_t)hwp[na]*QK_ROW;
      bf16x8 qf[5];
      #pragma unroll
      for (int c = 0; c < 5; ++c)
        qf[c] = ld_frag_b(qrow + c*32 + hi*8);
      f32x4 at[15];
      #pragma unroll
      for (int T = 0; T < 15; ++T){
        f32x4 acc = {0.f,0.f,0.f,0.f};
        #pragma unroll
        for (int c = 0; c < 5; ++c){
          bf16x8 kf = ld_frag_lds(kl, (T*16 + col)*KL_STRIDE + c*32 + hi*8);
          acc = MFMA(kf, qf[c], acc);             // att^T[m][n]
        }
        at[T] = acc;
      }
      const float sc = 0.12022458674074695f;      // log2(e)/12
      float M = -3.0e38f;
      #pragma unroll
      for (int T = 0; T < 15; ++T){
        #pragma unroll
        for (int jj = 0; jj < 4; ++jj){
          int m = T*16 + hi*4 + jj;
          if (m <= 224) M = fmaxf(M, at[T][jj]*sc);
        }
      }
      M = fmaxf(M, __shfl_xor(M, 16));
      M = fmaxf(M, __shfl_xor(M, 32));
      float Ssum = 0.f;
      #pragma unroll
      for (int T = 0; T < 15; ++T){
        #pragma unroll
        for (int jj = 0; jj < 4; ++jj){
          int m = T*16 + hi*4 + jj;
          float v = (m <= 224) ? exp2f(at[T][jj]*sc - M) : 0.f;
          at[T][jj] = v; Ssum += v;
        }
      }
      Ssum += __shfl_xor(Ssum, 16);
      Ssum += __shfl_xor(Ssum, 32);
      const float inv = 1.0f / Ssum;
      unsigned int plo[16], phi[16];
      #pragma unroll
      for (int T = 0; T < 15; ++T){
        plo[T] = (unsigned int)f2bf(at[T][0]*inv) | ((unsigned int)f2bf(at[T][1]*inv) << 16);
        phi[T] = (unsigned int)f2bf(at[T][2]*inv) | ((unsigned int)f2bf(at[T][3]*inv) << 16);
      }
      plo[15] = 0u; phi[15] = 0u;
      repack_frag(plo, phi, attf[slot], lane);
    }
  }

  // hoist per-slot store coords
  int pixs[2];
  #pragma unroll
  for (int slot = 0; slot < 2; ++slot){
    const int n = (wave + slot*8)*16 + col;
    pixs[slot] = (n <= 224) ? (int)hwp[n] : -1;
  }

  // ---- P2/P3: X from xbb into xl; PV partials bf16 ----
  unsigned int ylo[2][16], yhi[2][16];
  #pragma unroll
  for (int half = 0; half < 2; ++half){
    __syncthreads();
    for (int i = tid; i < 128*32; i += 512){
      int c = i >> 5, m8 = i & 31;
      uint4 v = make_uint4(0u,0u,0u,0u);
      if (m8 < 30)
        v = *(const uint4*)(xbw + (size_t)(half*128 + c)*XBB_ROW + m8*8);
      *(uint4*)(&xl[swz(c, m8*8)]) = v;
    }
    __syncthreads();
    #pragma unroll
    for (int slot = 0; slot < 2; ++slot){
      const int nt = wave + slot*8;
      if (nt < 15){
        #pragma unroll
        for (int ct = 0; ct < 8; ++ct){
          f32x4 acc = {0.f,0.f,0.f,0.f};
          #pragma unroll
          for (int k = 0; k < 8; ++k){
            bf16x8 xf = ld_frag_lds(xl, swz(ct*16 + col, k*32 + hi*8));
            acc = MFMA(xf, __builtin_bit_cast(bf16x8, attf[slot][k]), acc);
          }
          ylo[slot][half*8 + ct] = (unsigned int)f2bf(acc[0]) | ((unsigned int)f2bf(acc[1]) << 16);
          yhi[slot][half*8 + ct] = (unsigned int)f2bf(acc[2]) | ((unsigned int)f2bf(acc[3]) << 16);
        }
      }
    }
  }

  uint4 y1f[2][8];
  #pragma unroll
  for (int slot = 0; slot < 2; ++slot){
    const int nt = wave + slot*8;
    if (nt < 15)
      repack_frag(ylo[slot], yhi[slot], y1f[slot], lane);
  }

  // ---- P4: projection from wpb, 4 rounds x 64 rows + bf16 residual ----
  #pragma unroll 1
  for (int oe2 = 0; oe2 < 4; ++oe2){
    __syncthreads();                          // PV readers / prev wl readers done
    for (int i = tid; i < 64*32; i += 512){
      int olr = i >> 5, c8 = (i & 31)*8;
      *(uint4*)(&wl[swz(olr, c8)]) =
          *(const uint4*)(wpb + (size_t)(oe2*64 + olr)*256 + c8);
    }
    __syncthreads();
    #pragma unroll
    for (int ot = 0; ot < 4; ++ot){
      bf16x8 awf[8];
      const int olr = ot*16 + col;
      #pragma unroll
      for (int k = 0; k < 8; ++k)
        awf[k] = ld_frag_lds(wl, swz(olr, k*32 + hi*8));
      #pragma unroll
      for (int slot = 0; slot < 2; ++slot){
        const int nt = wave + slot*8;
        if (nt < 15){
          f32x4 y2 = {0.f,0.f,0.f,0.f};
          #pragma unroll
          for (int k = 0; k < 8; ++k)
            y2 = MFMA(awf[k], __builtin_bit_cast(bf16x8, y1f[slot][k]), y2);
          const int n = nt*16 + col;
          if (n <= 224){
            const size_t pix = (size_t)pixs[slot];
            #pragma unroll
            for (int jj = 0; jj < 4; ++jj){
              int o = oe2*64 + ot*16 + hi*4 + jj;
              float xr = bf2f(xbw[(size_t)o*XBB_ROW + n]);
              out[obase + (size_t)o*57600 + pix] = y2[jj] + xr;
            }
          }
        }
      }
    }
  }
}

// ---------------- small-ws fallback: R6-exact --------------------------------
__global__ __launch_bounds__(512) void k_qk(
    const float* __restrict__ x, const float* __restrict__ wq,
    const float* __restrict__ wk,
    unsigned short* __restrict__ qkws)
{
  __shared__ __align__(16) unsigned short S[32768];
  unsigned short* xt  = S;
  unsigned short* wqs = S;
  unsigned short* wks = S + 8192;
  const int wg  = blockIdx.x;
  const int b   = wg / 450;
  const int hw0 = (wg % 450) * 128;
  const int tid = threadIdx.x;
  const int lane = tid & 63, wave = tid >> 6;
  const int col  = lane & 15, hi = lane >> 4;

  {
    const float* xb = x + (size_t)b * 256 * 57600 + hw0;
    const int hw_l = tid & 127;
    #pragma unroll 4
    for (int i = 0; i < 32; ++i){
      int c = ((tid >> 7) * 32 + i) * 2;
      float f0 = xb[(size_t)c     * 57600 + hw_l];
      float f1 = xb[(size_t)(c+1) * 57600 + hw_l];
      *(unsigned int*)(&xt[swz(hw_l, c)]) =
          (unsigned int)f2bf(f0) | ((unsigned int)f2bf(f1) << 16);
    }
  }
  __syncthreads();

  bf16x8 af[8];
  const int arow = wave*16 + col;
  #pragma unroll
  for (int k = 0; k < 8; ++k)
    af[k] = ld_frag_lds(xt, swz(arow, k*32 + hi*8));

  const size_t orow_base = (size_t)b*57600 + hw0 + wave*16;

  for (int eg = 0; eg < 5; ++eg){
    __syncthreads();
    for (int i = 0; i < 8; ++i){
      int idx = tid + i*512;
      int e_l = idx >> 7, c = (idx & 127) * 2;
      int e = eg*32 + e_l;
      float2 vq = make_float2(0.f,0.f), vk = make_float2(0.f,0.f);
      if (e < 144){
        vq = *(const float2*)(wq + (size_t)e*256 + c);
        vk = *(const float2*)(wk + (size_t)e*256 + c);
      }
      *(unsigned int*)(&wqs[swz(e_l, c)]) =
          (unsigned int)f2bf(vq.x) | ((unsigned int)f2bf(vq.y) << 16);
      *(unsigned int*)(&wks[swz(e_l, c)]) =
          (unsigned int)f2bf(vk.x) | ((unsigned int)f2bf(vk.y) << 16);
    }
    __syncthreads();
    #pragma unroll
    for (int etl = 0; etl < 2; ++etl){
      f32x4 aq = {0.f,0.f,0.f,0.f}, ak = {0.f,0.f,0.f,0.f};
      const int el = etl*16 + col;
      #pragma unroll
      for (int k = 0; k < 8; ++k){
        int idx = swz(el, k*32 + hi*8);
        bf16x8 bq = ld_frag_lds(wqs, idx);
        bf16x8 bk = ld_frag_lds(wks, idx);
        aq = MFMA(af[k], bq, aq);
        ak = MFMA(af[k], bk, ak);
      }
      const int e_out = eg*32 + etl*16 + col;
      #pragma unroll
      for (int jj = 0; jj < 4; ++jj){
        size_t row = orow_base + hi*4 + jj;
        qkws[row*QK_ROW + e_out]       = f2bf(aq[jj]);
        qkws[row*QK_ROW + 160 + e_out] = f2bf(ak[jj]);
      }
    }
  }
}

__global__ __launch_bounds__(512,4) void k_attn_s(
    const float* __restrict__ x, const float* __restrict__ wproj,
    const unsigned short* __restrict__ qkws, float* __restrict__ out)
{
  __shared__ __align__(16) unsigned short S[40320 + 480];
  unsigned short* kl = S;
  unsigned short* xl = S;
  unsigned short* wl = S + 32768;
  unsigned int*  hwp = (unsigned int*)(S + 40320);
  const int wg = blockIdx.x;
  const int b  = wg >> 8;
  const int th = (wg >> 4) & 15, tw = wg & 15;
  const int h0 = th*15, w0 = tw*15;
  const int tid = threadIdx.x;
  const int lane = tid & 63, wave = tid >> 6;
  const int col  = lane & 15, hi = lane >> 4;
  const size_t xbase = (size_t)b * 256 * 57600;
  const unsigned short* qkb = qkws + (size_t)b * 57600 * QK_ROW;

  if (tid < 240){
    int ms = tid <= 224 ? tid : 224;
    hwp[tid] = (unsigned int)((h0 + ms/15)*240 + w0 + ms%15);
  }
  __syncthreads();

  for (int i = tid; i < 240*20; i += 512){
    int m = i / 20, eb = i - m*20;
    *(uint4*)(&kl[m*KL_STRIDE + eb*8]) =
        *(const uint4*)(qkb + (size_t)hwp[m]*QK_ROW + 160 + eb*8);
  }
  __syncthreads();

  uint4 attf[2][8];
  #pragma unroll
  for (int slot = 0; slot < 2; ++slot){
    const int nt = wave + slot*8;
    if (nt < 15){
      const int n  = nt*16 + col;
      const int na = n <= 224 ? n : 224;
      const unsigned short* qrow = qkb + (size_t)hwp[na]*QK_ROW;
      bf16x8 qf[5];
      #pragma unroll
      for (int c = 0; c < 5; ++c)
        qf[c] = ld_frag_b(qrow + c*32 + hi*8);
      f32x4 at[15];
      #pragma unroll
      for (int T = 0; T < 15; ++T){
        f32x4 acc = {0.f,0.f,0.f,0.f};
        #pragma unroll
        for (int c = 0; c < 5; ++c){
          bf16x8 kf = ld_frag_lds(kl, (T*16 + col)*KL_STRIDE + c*32 + hi*8);
          acc = MFMA(kf, qf[c], acc);
        }
        at[T] = acc;
      }
      const float sc = 0.12022458674074695f;
      float M = -3.0e38f;
      #pragma unroll
      for (int T = 0; T < 15; ++T){
        #pragma unroll
        for (int jj = 0; jj < 4; ++jj){
          int m = T*16 + hi*4 + jj;
          if (m <= 224) M = fmaxf(M, at[T][jj]*sc);
        }
      }
      M = fmaxf(M, __shfl_xor(M, 16));
      M = fmaxf(M, __shfl_xor(M, 32));
      float Ssum = 0.f;
      #pragma unroll
      for (int T = 0; T < 15; ++T){
        #pragma unroll
        for (int jj = 0; jj < 4; ++jj){
          int m = T*16 + hi*4 + jj;
          float v = (m <= 224) ? exp2f(at[T][jj]*sc - M) : 0.f;
          at[T][jj] = v; Ssum += v;
        }
      }
      Ssum += __shfl_xor(Ssum, 16);
      Ssum += __shfl_xor(Ssum, 32);
      const float inv = 1.0f / Ssum;
      unsigned int plo[16], phi[16];
      #pragma unroll
      for (int T = 0; T < 15; ++T){
        plo[T] = (unsigned int)f2bf(at[T][0]*inv) | ((unsigned int)f2bf(at[T][1]*inv) << 16);
        phi[T] = (unsigned int)f2bf(at[T][2]*inv) | ((unsigned int)f2bf(at[T][3]*inv) << 16);
      }
      plo[15] = 0u; phi[15] = 0u;
      repack_frag(plo, phi, attf[slot], lane);
    }
  }

  unsigned int ylo[2][16], yhi[2][16];
  #pragma unroll
  for (int half = 0; half < 2; ++half){
    __syncthreads();
    for (int i = tid; i < 128*128; i += 512){
      int c = i >> 7, m = (i & 127)*2;
      int m0 = m <= 224 ? m : 224;
      float f0 = (m     <= 224) ? x[xbase + (size_t)(half*128 + c)*57600 + hwp[m0]]   : 0.f;
      float f1 = (m + 1 <= 224) ? x[xbase + (size_t)(half*128 + c)*57600 + hwp[m0+1]] : 0.f;
      *(unsigned int*)(&xl[swz(c, m)]) =
          (unsigned int)f2bf(f0) | ((unsigned int)f2bf(f1) << 16);
    }
    __syncthreads();
    #pragma unroll
    for (int slot = 0; slot < 2; ++slot){
      const int nt = wave + slot*8;
      if (nt < 15){
        #pragma unroll
        for (int ct = 0; ct < 8; ++ct){
          f32x4 acc = {0.f,0.f,0.f,0.f};
          #pragma unroll
          for (int k = 0; k < 8; ++k){
            bf16x8 xf = ld_frag_lds(xl, swz(ct*16 + col, k*32 + hi*8));
            acc = MFMA(xf, __builtin_bit_cast(bf16x8, attf[slot][k]), acc);
          }
          ylo[slot][half*8 + ct] = (unsigned int)f2bf(acc[0]) | ((unsigned int)f2bf(acc[1]) << 16);
          yhi[slot][half*8 + ct] = (unsigned int)f2bf(acc[2]) | ((unsigned int)f2bf(acc[3]) << 16);
        }
      }
    }
  }

  uint4 y1f[2][8];
  #pragma unroll
  for (int slot = 0; slot < 2; ++slot){
    const int nt = wave + slot*8;
    if (nt < 15)
      repack_frag(ylo[slot], yhi[slot], y1f[slot], lane);
  }

  #pragma unroll 1
  for (int oe = 0; oe < 16; ++oe){
    __syncthreads();
    for (int i = tid; i < 16*128; i += 512){
      int olr = i >> 7, c = (i & 127)*2;
      const float* wr = wproj + (size_t)(oe*16 + olr)*256 + c;
      *(unsigned int*)(&wl[swz(olr, c)]) =
          (unsigned int)f2bf(wr[0]) | ((unsigned int)f2bf(wr[1]) << 16);
    }
    __syncthreads();
    bf16x8 awf[8];
    #pragma unroll
    for (int k = 0; k < 8; ++k)
      awf[k] = ld_frag_lds(wl, swz(col, k*32 + hi*8));
    #pragma unroll
    for (int slot = 0; slot < 2; ++slot){
      const int nt = wave + slot*8;
      if (nt < 15){
        f32x4 y2 = {0.f,0.f,0.f,0.f};
        #pragma unroll
        for (int k = 0; k < 8; ++k)
          y2 = MFMA(awf[k], __builtin_bit_cast(bf16x8, y1f[slot][k]), y2);
        const int n = nt*16 + col;
        if (n <= 224){
          const size_t pix = hwp[n];
          #pragma unroll
          for (int jj = 0; jj < 4; ++jj){
            int o = oe*16 + hi*4 + jj;
            const size_t idx = xbase + (size_t)o*57600 + pix;
            out[idx] = y2[jj] + x[idx];
          }
        }
      }
    }
  }
}

extern "C" void kernel_launch(void* const* d_in, const int* in_sizes, int n_in,
                              void* d_out, int out_size, void* d_ws, size_t ws_size,
                              hipStream_t stream)
{
  const float* x     = (const float*)d_in[0];
  const float* wq    = (const float*)d_in[1];
  const float* wk    = (const float*)d_in[2];
  const float* wproj = (const float*)d_in[3];
  float* out = (float*)d_out;
  (void)in_sizes; (void)n_in; (void)out_size;

  const size_t QKWS_B = (size_t)8*57600*QK_ROW*2;        // 294,912,000
  const size_t XBB_B  = (size_t)8*256*256*XBB_ROW*2;     // 251,658,240
  const size_t WB_ALL = (size_t)(160*256 + 160*256 + 256*256)*2;  // 294,912
  unsigned short* qkws = (unsigned short*)d_ws;

  if (ws_size >= QKWS_B + XBB_B + WB_ALL){                // confirmed fits (R10)
    unsigned short* xbb = (unsigned short*)((char*)d_ws + QKWS_B);
    unsigned short* wqb = (unsigned short*)((char*)d_ws + QKWS_B + XBB_B);
    unsigned short* wkb = wqb + 160*256;
    unsigned short* wpb = wkb + 160*256;
    k_w    <<<dim3(288),  dim3(256), 0, stream>>>(wq, wk, wproj, wqb, wkb, wpb);
    k_xb   <<<dim3(4096), dim3(256), 0, stream>>>(x, xbb);
    k_fused<<<dim3(2048), dim3(512), 0, stream>>>(xbb, wqb, wkb, wpb, qkws, out);
  } else {
    k_qk    <<<dim3(3600), dim3(512), 0, stream>>>(x, wq, wk, qkws);
    k_attn_s<<<dim3(2048), dim3(512), 0, stream>>>(x, wproj, qkws, out);
  }
}